// Round 8
// baseline (647.763 us; speedup 1.0000x reference)
//
#include <hip/hip_runtime.h>
#include <hip/hip_fp16.h>
#include <math.h>

// Problem constants
#define NQ 40000

typedef short s16x8 __attribute__((ext_vector_type(8)));
typedef float f32x4 __attribute__((ext_vector_type(4)));

static constexpr int HLa[4] = {128, 64, 32, 16};
static constexpr int HWa[4] = {16384, 4096, 1024, 256};
// v bases (element units): level block is [HH][Hl][Wl][32]
static constexpr int VB[4] = {0, 4194304, 5242880, 5505024};
// total v elements = 5570560

__device__ __forceinline__ short bf16hi(float x) {
    union { float f; unsigned u; } v; v.f = x;
    unsigned r = v.u + 0x7FFFu + ((v.u >> 16) & 1u);
    return (short)(r >> 16);
}
__device__ __forceinline__ float bf16f(short s) {
    union { unsigned u; float f; } v; v.u = ((unsigned)(unsigned short)s) << 16;
    return v.f;
}
__device__ __forceinline__ float fast_tanh(float x) {
    float xc = fminf(fmaxf(x, -15.f), 15.f);
    float e = __expf(2.f * xc);
    return (e - 1.f) / (e + 1.f);
}
// record-array bank swizzles (bank = s%32 was q-independent -> 8-way conflict)
__device__ __forceinline__ int swzPI(int s) { return s ^ (((s >> 6) & 3) << 3); }
__device__ __forceinline__ int swzPW(int s) { return s ^ (((s >> 6) & 3) << 2); }
#define MFMA16(a, b, c) __builtin_amdgcn_mfma_f32_16x16x32_bf16(a, b, c, 0, 0, 0)

// ---------------------------------------------------------------------------
// Kernel 0: weight prep — transpose [C][N] -> [N][C], bf16 hi/lo split.
// rows: [0,512) = W_off cols, [512,768) = W_attn cols, [768,1024) = W_out cols
// ---------------------------------------------------------------------------
__global__ __launch_bounds__(256) void prep_w(
    const float* __restrict__ Woff, const float* __restrict__ Wattn,
    const float* __restrict__ Wout, short* __restrict__ WtH, short* __restrict__ WtL)
{
    int r = blockIdx.x, c = threadIdx.x;
    float x;
    if (r < 512)      x = Woff[c * 512 + r];
    else if (r < 768) x = Wattn[c * 256 + (r - 512)];
    else              x = Wout[c * 256 + (r - 768)];
    short hi = bf16hi(x);
    WtH[r * 256 + c] = hi;
    WtL[r * 256 + c] = bf16hi(x - bf16f(hi));
}

// ---------------------------------------------------------------------------
// Kernel 1: value projection -> fp16 table  v[l][hh][y][x][dd]
// ---------------------------------------------------------------------------
__global__ __launch_bounds__(256) void vproj_kernel(
    const float* __restrict__ f0, const float* __restrict__ f1,
    const float* __restrict__ f2, const float* __restrict__ f3,
    const float* __restrict__ Wv, const float* __restrict__ bv,
    __half* __restrict__ v)
{
    __shared__ float fT[256 * 16];  // [c][hw] 16KB

    int bid = blockIdx.x;
    const float* f;
    int base, HWl, hw0;
    if (bid < 1024)      { f = f0; base = VB[0]; HWl = 16384; hw0 = bid * 16; }
    else if (bid < 1280) { f = f1; base = VB[1]; HWl = 4096;  hw0 = (bid - 1024) * 16; }
    else if (bid < 1344) { f = f2; base = VB[2]; HWl = 1024;  hw0 = (bid - 1280) * 16; }
    else                 { f = f3; base = VB[3]; HWl = 256;   hw0 = (bid - 1344) * 16; }

    int t = threadIdx.x;
    for (int k = 0; k < 16; ++k) {
        int idx = k * 256 + t;
        int c = idx >> 4, j = idx & 15;
        fT[idx] = f[c * HWl + hw0 + j];
    }
    __syncthreads();

    int to4 = (t & 63) * 4;
    int hw4 = (t >> 6) * 4;

    float4 bv4 = *(const float4*)(bv + to4);
    float acc[4][4];
    #pragma unroll
    for (int i = 0; i < 4; ++i) {
        acc[i][0] = bv4.x; acc[i][1] = bv4.y; acc[i][2] = bv4.z; acc[i][3] = bv4.w;
    }

    #pragma unroll 4
    for (int c = 0; c < 256; ++c) {
        float4 w4 = *(const float4*)(Wv + c * 256 + to4);
        float4 fv = *(const float4*)(fT + c * 16 + hw4);
        float fa[4] = {fv.x, fv.y, fv.z, fv.w};
        float wa[4] = {w4.x, w4.y, w4.z, w4.w};
        #pragma unroll
        for (int i = 0; i < 4; ++i)
            #pragma unroll
            for (int j = 0; j < 4; ++j)
                acc[i][j] += fa[i] * wa[j];
    }

    int hh = to4 >> 5, dd4 = to4 & 31;
    #pragma unroll
    for (int i = 0; i < 4; ++i) {
        int hw = hw0 + hw4 + i;
        __half2 h0 = __floats2half2_rn(acc[i][0], acc[i][1]);
        __half2 h1 = __floats2half2_rn(acc[i][2], acc[i][3]);
        uint2 st = make_uint2(*(unsigned*)&h0, *(unsigned*)&h1);
        *(uint2*)(v + base + (hh * HWl + hw) * 32 + dd4) = st;
    }
}

// ---------------------------------------------------------------------------
// Kernel 2: MFMA logits (hi/lo) -> fp32 softmax -> per-pass LDS dump ->
//           parallel pack -> 8-lane gather (pk-fp16 blend, fp32 accum) ->
//           MFMA out proj -> LDS-staged coalesced store
// block = 256 threads (4 waves), 16 queries, 2500 blocks. LDS 37.25 KB.
// ---------------------------------------------------------------------------
__global__ __launch_bounds__(256, 4) void msda_kernel(
    const float* __restrict__ query, const float* __restrict__ refp,
    const float* __restrict__ boff,  const float* __restrict__ battn,
    const float* __restrict__ bout,
    const short* __restrict__ WtH,   const short* __restrict__ WtL,
    const __half* __restrict__ v,    float* __restrict__ out)
{
    __shared__ __align__(16) char lds[38144];
    short*    sQh  = (short*)lds;                // [16][264] bf16 hi (A-frags)
    short*    sQl  = (short*)(lds + 8448);       // [16][264] bf16 lo
    float*    offL = (float*)lds;                // [16][132] pass off-logits (alias sQh)
    uint2*    sPWh = (uint2*)(lds + 8448);       // [1024] fp16 corner-wt pairs (alias sQl)
    float*    sWf  = (float*)(lds + 16896);      // [16][260] fp32 attn wts -> preT -> out stage
    unsigned* sPI  = (unsigned*)(lds + 33536);   // [1024] packed idx|dx|dy
    float*    sR   = (float*)(lds + 37632);      // [128] ref points

    const int t = threadIdx.x;
    const int n0 = blockIdx.x * 16;
    const int wv = t >> 6, lane = t & 63;
    const int mrow = lane & 15, kg = lane >> 4;

    // ---- Stage: query -> bf16 hi/lo LDS, ref points ----
    for (int k2 = 0; k2 < 16; ++k2) {
        float x = query[(n0 + k2) * 256 + t];
        short hi = bf16hi(x);
        sQh[k2 * 264 + t] = hi;
        sQl[k2 * 264 + t] = bf16hi(x - bf16f(hi));
    }
    if (t < 128) sR[t] = refp[n0 * 8 + t];
    __syncthreads();

    // ---- Phase B: logits via MFMA (hi/lo 3-pass for off AND attn) ----
    f32x4 accO[8], accA[4];
    {
        f32x4 z = {0.f, 0.f, 0.f, 0.f};
        #pragma unroll
        for (int j = 0; j < 8; ++j) accO[j] = z;
        #pragma unroll
        for (int j = 0; j < 4; ++j) accA[j] = z;
    }
    {
        const short* offH = WtH + (wv * 128 + mrow) * 256 + kg * 8;
        const short* offLo = WtL + (wv * 128 + mrow) * 256 + kg * 8;
        const short* attH = WtH + (512 + wv * 64 + mrow) * 256 + kg * 8;
        const short* attL = WtL + (512 + wv * 64 + mrow) * 256 + kg * 8;
        const int aoff = mrow * 264 + kg * 8;
        #pragma unroll
        for (int kk = 0; kk < 8; ++kk) {
            s16x8 ah = *(const s16x8*)(sQh + aoff + kk * 32);
            s16x8 al = *(const s16x8*)(sQl + aoff + kk * 32);
            #pragma unroll
            for (int j = 0; j < 8; ++j) {
                s16x8 bh = *(const s16x8*)(offH + j * 4096 + kk * 32);
                s16x8 bl = *(const s16x8*)(offLo + j * 4096 + kk * 32);
                accO[j] = MFMA16(ah, bh, accO[j]);
                accO[j] = MFMA16(al, bh, accO[j]);
                accO[j] = MFMA16(ah, bl, accO[j]);
            }
            #pragma unroll
            for (int ja = 0; ja < 4; ++ja) {
                s16x8 bh = *(const s16x8*)(attH + ja * 4096 + kk * 32);
                s16x8 bl = *(const s16x8*)(attL + ja * 4096 + kk * 32);
                accA[ja] = MFMA16(ah, bh, accA[ja]);
                accA[ja] = MFMA16(al, bh, accA[ja]);
                accA[ja] = MFMA16(ah, bl, accA[ja]);
            }
        }
    }
    // biases (per-column; D layout: col = mrow, rows = kg*4 + r)
    #pragma unroll
    for (int j = 0; j < 8; ++j) {
        float bb = boff[wv * 128 + j * 16 + mrow];
        #pragma unroll
        for (int r = 0; r < 4; ++r) accO[j][r] += bb;
    }
    #pragma unroll
    for (int ja = 0; ja < 4; ++ja) {
        float bb = battn[wv * 64 + ja * 16 + mrow];
        #pragma unroll
        for (int r = 0; r < 4; ++r) accA[ja][r] += bb;
    }

    // ---- Softmax over P=8 (8-lane groups), fp32 weights to sWf ----
    #pragma unroll
    for (int ja = 0; ja < 4; ++ja) {
        int hh = 2 * wv + (ja >> 1);
        int l  = ((ja & 1) << 1) | (mrow >> 3);
        int p  = mrow & 7;
        #pragma unroll
        for (int r = 0; r < 4; ++r) {
            float x = accA[ja][r];
            float m = fmaxf(x, __shfl_xor(x, 1));
            m = fmaxf(m, __shfl_xor(m, 2));
            m = fmaxf(m, __shfl_xor(m, 4));
            float e = __expf(x - m);
            float s = e + __shfl_xor(e, 1);
            s += __shfl_xor(s, 2);
            s += __shfl_xor(s, 4);
            int q = kg * 4 + r;
            sWf[q * 260 + hh * 32 + l * 8 + p] = e / s;
        }
    }
    __syncthreads();

    // ---- Pass loop over hh-pairs {2k, 2k+1} ----
    const int clS  = t & 7;          // channel quad: ch [4*clS, 4*clS+4)
    const int hhLS = (t >> 3) & 1;   // head within pair
    const int qS   = t >> 4;         // query 0..15

    for (int k = 0; k < 4; ++k) {
        // -- dump: wave k writes its off-logits to offL[q][col] (verified D map) --
        if (wv == k) {
            #pragma unroll
            for (int j = 0; j < 8; ++j)
                #pragma unroll
                for (int r = 0; r < 4; ++r)
                    offL[(kg * 4 + r) * 132 + j * 16 + mrow] = accO[j][r];
        }
        __syncthreads();

        // -- pack: all 256 threads, 4 samples each, plain index math --
        #pragma unroll
        for (int it = 0; it < 4; ++it) {
            int s = it * 256 + t;               // = q*64 + hhL*32 + l*8 + p
            int q = s >> 6, hhL = (s >> 5) & 1, l = (s >> 3) & 3, p = s & 7;
            const int Wl = 128 >> l;
            const float scl = 0.5f * (float)(Wl - 1);
            float lx = offL[q * 132 + hhL * 64 + l * 16 + p * 2];
            float ly = offL[q * 132 + hhL * 64 + l * 16 + p * 2 + 1];
            float w  = sWf[q * 260 + (2 * k + hhL) * 32 + l * 8 + p];
            float rx = sR[q * 8 + l * 2], ry = sR[q * 8 + l * 2 + 1];
            float cx = rx + fast_tanh(lx) * 0.25f;
            float cy = ry + fast_tanh(ly) * 0.25f;
            float xx = (cx + 1.f) * scl, yy = (cy + 1.f) * scl;
            float x0f = floorf(xx), y0f = floorf(yy);
            float fx = xx - x0f, fy = yy - y0f;
            int x0 = (int)x0f, y0 = (int)y0f;
            int xc0 = min(max(x0, 0), Wl - 1);
            int xc1 = min(max(x0 + 1, 0), Wl - 1);
            int yc0 = min(max(y0, 0), Wl - 1);
            int yc1 = min(max(y0 + 1, 0), Wl - 1);
            bool bx0 = (x0 >= 0) & (x0 < Wl);
            bool bx1 = (x0 + 1 >= 0) & (x0 + 1 < Wl);
            bool by0 = (y0 >= 0) & (y0 < Wl);
            bool by1 = (y0 + 1 >= 0) & (y0 + 1 < Wl);
            float w00 = (bx0 && by0) ? (1.f - fx) * (1.f - fy) * w : 0.f;
            float w01 = (bx1 && by0) ? fx * (1.f - fy) * w : 0.f;
            float w10 = (bx0 && by1) ? (1.f - fx) * fy * w : 0.f;
            float w11 = (bx1 && by1) ? fx * fy * w : 0.f;
            unsigned pw = (unsigned)(yc0 * Wl + xc0)
                        | ((unsigned)(xc1 - xc0) << 14)
                        | ((unsigned)(yc1 - yc0) << 15);
            sPI[swzPI(s)] = pw;
            __half2 hA = __floats2half2_rn(w00, w01);
            __half2 hB = __floats2half2_rn(w10, w11);
            sPWh[swzPW(s)] = make_uint2(*(unsigned*)&hA, *(unsigned*)&hB);
        }
        __syncthreads();

        // -- sample: 8 lanes per sample, 8B gathers, pk-fp16 blend, fp32 accum --
        {
            const int hh = 2 * k + hhLS;
            float ac0 = 0.f, ac1 = 0.f, ac2 = 0.f, ac3 = 0.f;
            #pragma unroll
            for (int l = 0; l < 4; ++l) {
                const int Wl = HLa[l];
                const __half2* vl = (const __half2*)(v + VB[l] + hh * HWa[l] * 32 + clS * 4);
                const int sbase = qS * 64 + hhLS * 32 + l * 8;
                #pragma unroll
                for (int p = 0; p < 8; ++p) {
                    unsigned pw = sPI[swzPI(sbase + p)];
                    uint2 ww = sPWh[swzPW(sbase + p)];
                    int idx = pw & 0x3FFF;
                    int dxo = ((pw >> 14) & 1) * 16;
                    int dyo = ((pw >> 15) & 1) * (Wl * 16);
                    const __half2* b00 = vl + idx * 16;
                    uint2 g00 = *(const uint2*)(b00);
                    uint2 g01 = *(const uint2*)(b00 + dxo);
                    uint2 g10 = *(const uint2*)(b00 + dyo);
                    uint2 g11 = *(const uint2*)(b00 + dxo + dyo);
                    __half2 wA = *(__half2*)&ww.x;   // (w00, w01)
                    __half2 wB = *(__half2*)&ww.y;   // (w10, w11)
                    __half2 w00 = __low2half2(wA),  w01 = __high2half2(wA);
                    __half2 w10 = __low2half2(wB),  w11 = __high2half2(wB);
                    __half2 s0 = __hmul2(w00, *(__half2*)&g00.x);
                    s0 = __hfma2(w01, *(__half2*)&g01.x, s0);
                    s0 = __hfma2(w10, *(__half2*)&g10.x, s0);
                    s0 = __hfma2(w11, *(__half2*)&g11.x, s0);
                    __half2 s1 = __hmul2(w00, *(__half2*)&g00.y);
                    s1 = __hfma2(w01, *(__half2*)&g01.y, s1);
                    s1 = __hfma2(w10, *(__half2*)&g10.y, s1);
                    s1 = __hfma2(w11, *(__half2*)&g11.y, s1);
                    float2 f0 = __half22float2(s0);
                    float2 f1 = __half22float2(s1);
                    ac0 += f0.x; ac1 += f0.y; ac2 += f1.x; ac3 += f1.y;
                }
            }
            // preT cols [64k, 64k+64) — attn-weight cols for passes > k
            // live at >= 64(k+1): disjoint.
            *(float4*)(sWf + qS * 260 + hh * 32 + clS * 4) =
                make_float4(ac0, ac1, ac2, ac3);
        }
        __syncthreads();
    }

    // ---- E-stage: preT (fp32) -> bf16 hi/lo, then MFMA out projection ----
    {
        int q = t & 15, seg = t >> 4;        // row q, cols [seg*16, seg*16+16)
        const float* src = sWf + q * 260 + seg * 16;
        short* dh = sQh + q * 264 + seg * 16;
        short* dl = sQl + q * 264 + seg * 16;
        #pragma unroll
        for (int jj = 0; jj < 8; ++jj) {
            float2 f = *(const float2*)(src + 2 * jj);
            short h0 = bf16hi(f.x), h1 = bf16hi(f.y);
            dh[2 * jj]     = h0;
            dh[2 * jj + 1] = h1;
            dl[2 * jj]     = bf16hi(f.x - bf16f(h0));
            dl[2 * jj + 1] = bf16hi(f.y - bf16f(h1));
        }
    }
    __syncthreads();

    {
        f32x4 accE[4];
        f32x4 z = {0.f, 0.f, 0.f, 0.f};
        #pragma unroll
        for (int e = 0; e < 4; ++e) accE[e] = z;
        const short* outH = WtH + (768 + wv * 64 + mrow) * 256 + kg * 8;
        const short* outL = WtL + (768 + wv * 64 + mrow) * 256 + kg * 8;
        const int aoff = mrow * 264 + kg * 8;
        #pragma unroll
        for (int kk = 0; kk < 8; ++kk) {
            s16x8 ah = *(const s16x8*)(sQh + aoff + kk * 32);
            s16x8 al = *(const s16x8*)(sQl + aoff + kk * 32);
            #pragma unroll
            for (int e = 0; e < 4; ++e) {
                s16x8 bh = *(const s16x8*)(outH + e * 4096 + kk * 32);
                s16x8 bl = *(const s16x8*)(outL + e * 4096 + kk * 32);
                accE[e] = MFMA16(ah, bh, accE[e]);
                accE[e] = MFMA16(al, bh, accE[e]);
                accE[e] = MFMA16(ah, bl, accE[e]);
            }
        }
        // stage to LDS (sWf dead) for coalesced global stores
        #pragma unroll
        for (int e = 0; e < 4; ++e) {
            int col = wv * 64 + e * 16 + mrow;
            float bb = bout[col];
            #pragma unroll
            for (int r = 0; r < 4; ++r)
                sWf[(kg * 4 + r) * 260 + col] = accE[e][r] + bb;
        }
    }
    __syncthreads();
    {
        int q = t >> 4, c0 = (t & 15) * 4;
        #pragma unroll
        for (int cb = 0; cb < 4; ++cb) {
            float4 vv = *(const float4*)(sWf + q * 260 + cb * 64 + c0);
            *(float4*)(out + (n0 + q) * 256 + cb * 64 + c0) = vv;
        }
    }
}

// ---------------------------------------------------------------------------
extern "C" void kernel_launch(void* const* d_in, const int* in_sizes, int n_in,
                              void* d_out, int out_size, void* d_ws, size_t ws_size,
                              hipStream_t stream) {
    const float* query = (const float*)d_in[0];
    const float* refp  = (const float*)d_in[1];
    const float* f0    = (const float*)d_in[2];
    const float* f1    = (const float*)d_in[3];
    const float* f2    = (const float*)d_in[4];
    const float* f3    = (const float*)d_in[5];
    const float* Woff  = (const float*)d_in[6];
    const float* boff  = (const float*)d_in[7];
    const float* Wattn = (const float*)d_in[8];
    const float* battn = (const float*)d_in[9];
    const float* Wval  = (const float*)d_in[10];
    const float* bval  = (const float*)d_in[11];
    const float* Wout  = (const float*)d_in[12];
    const float* bout  = (const float*)d_in[13];

    __half* v  = (__half*)d_ws;                              // 11,141,120 B
    short* WtH = (short*)((char*)d_ws + 11141120);           //    524,288 B
    short* WtL = WtH + 262144;                               //    524,288 B
    float* outp = (float*)d_out;

    prep_w<<<1024, 256, 0, stream>>>(Woff, Wattn, Wout, WtH, WtL);
    vproj_kernel<<<1360, 256, 0, stream>>>(f0, f1, f2, f3, Wval, bval, v);
    msda_kernel<<<2500, 256, 0, stream>>>(query, refp, boff, battn, bout,
                                          WtH, WtL, v, outp);
}

// Round 10
// 575.321 us; speedup vs baseline: 1.1259x; 1.1259x over previous
//
#include <hip/hip_runtime.h>
#include <hip/hip_fp16.h>
#include <math.h>

// Problem constants
#define NQ 40000

typedef short s16x8 __attribute__((ext_vector_type(8)));
typedef float f32x4 __attribute__((ext_vector_type(4)));

static constexpr int HLa[4] = {128, 64, 32, 16};
static constexpr int HWa[4] = {16384, 4096, 1024, 256};
// v bases (element units): level block is [HH][Hl][Wl][32]
static constexpr int VB[4] = {0, 4194304, 5242880, 5505024};
// total v elements = 5570560

__device__ __forceinline__ short bf16hi(float x) {
    union { float f; unsigned u; } v; v.f = x;
    unsigned r = v.u + 0x7FFFu + ((v.u >> 16) & 1u);
    return (short)(r >> 16);
}
__device__ __forceinline__ float bf16f(short s) {
    union { unsigned u; float f; } v; v.u = ((unsigned)(unsigned short)s) << 16;
    return v.f;
}
__device__ __forceinline__ float fast_tanh(float x) {
    float xc = fminf(fmaxf(x, -15.f), 15.f);
    float e = __expf(2.f * xc);
    return (e - 1.f) / (e + 1.f);
}
#define MFMA16(a, b, c) __builtin_amdgcn_mfma_f32_16x16x32_bf16(a, b, c, 0, 0, 0)

// ---------------------------------------------------------------------------
// Kernel 0: weight prep — transpose [C][N] -> [N][C], bf16 hi/lo split.
// rows: [0,512) = W_off cols, [512,768) = W_attn cols, [768,1024) = W_out cols
// ---------------------------------------------------------------------------
__global__ __launch_bounds__(256) void prep_w(
    const float* __restrict__ Woff, const float* __restrict__ Wattn,
    const float* __restrict__ Wout, short* __restrict__ WtH, short* __restrict__ WtL)
{
    int r = blockIdx.x, c = threadIdx.x;
    float x;
    if (r < 512)      x = Woff[c * 512 + r];
    else if (r < 768) x = Wattn[c * 256 + (r - 512)];
    else              x = Wout[c * 256 + (r - 768)];
    short hi = bf16hi(x);
    WtH[r * 256 + c] = hi;
    WtL[r * 256 + c] = bf16hi(x - bf16f(hi));
}

// ---------------------------------------------------------------------------
// Kernel 1: value projection -> fp16 table  v[l][hh][y][x][dd]
// ---------------------------------------------------------------------------
__global__ __launch_bounds__(256) void vproj_kernel(
    const float* __restrict__ f0, const float* __restrict__ f1,
    const float* __restrict__ f2, const float* __restrict__ f3,
    const float* __restrict__ Wv, const float* __restrict__ bv,
    __half* __restrict__ v)
{
    __shared__ float fT[256 * 16];  // [c][hw] 16KB

    int bid = blockIdx.x;
    const float* f;
    int base, HWl, hw0;
    if (bid < 1024)      { f = f0; base = VB[0]; HWl = 16384; hw0 = bid * 16; }
    else if (bid < 1280) { f = f1; base = VB[1]; HWl = 4096;  hw0 = (bid - 1024) * 16; }
    else if (bid < 1344) { f = f2; base = VB[2]; HWl = 1024;  hw0 = (bid - 1280) * 16; }
    else                 { f = f3; base = VB[3]; HWl = 256;   hw0 = (bid - 1344) * 16; }

    int t = threadIdx.x;
    for (int k = 0; k < 16; ++k) {
        int idx = k * 256 + t;
        int c = idx >> 4, j = idx & 15;
        fT[idx] = f[c * HWl + hw0 + j];
    }
    __syncthreads();

    int to4 = (t & 63) * 4;
    int hw4 = (t >> 6) * 4;

    float4 bv4 = *(const float4*)(bv + to4);
    float acc[4][4];
    #pragma unroll
    for (int i = 0; i < 4; ++i) {
        acc[i][0] = bv4.x; acc[i][1] = bv4.y; acc[i][2] = bv4.z; acc[i][3] = bv4.w;
    }

    #pragma unroll 4
    for (int c = 0; c < 256; ++c) {
        float4 w4 = *(const float4*)(Wv + c * 256 + to4);
        float4 fv = *(const float4*)(fT + c * 16 + hw4);
        float fa[4] = {fv.x, fv.y, fv.z, fv.w};
        float wa[4] = {w4.x, w4.y, w4.z, w4.w};
        #pragma unroll
        for (int i = 0; i < 4; ++i)
            #pragma unroll
            for (int j = 0; j < 4; ++j)
                acc[i][j] += fa[i] * wa[j];
    }

    int hh = to4 >> 5, dd4 = to4 & 31;
    #pragma unroll
    for (int i = 0; i < 4; ++i) {
        int hw = hw0 + hw4 + i;
        __half2 h0 = __floats2half2_rn(acc[i][0], acc[i][1]);
        __half2 h1 = __floats2half2_rn(acc[i][2], acc[i][3]);
        uint2 st = make_uint2(*(unsigned*)&h0, *(unsigned*)&h1);
        *(uint2*)(v + base + (hh * HWl + hw) * 32 + dd4) = st;
    }
}

// ---------------------------------------------------------------------------
// Kernel 2: MFMA logits -> per-wave logit dump -> softmax -> WAVE-AUTONOMOUS
//           per-query {pack 64 records -> 16-lane gather/blend} (no block
//           barriers in hot loop) -> fp16 preT -> MFMA out proj.
// block = 256 threads (4 waves), 16 queries, 2500 blocks. LDS 54,272 B.
// LDS overlap audit: offW (0..33792) aliases sQh/sQl (dead between the
// post-GEMM syncthreads and the post-chunk-loop syncthreads); preT/sWh/
// records/sR live in fresh space, no aliasing.
// ---------------------------------------------------------------------------
__global__ __launch_bounds__(256, 3) void msda_kernel(
    const float* __restrict__ query, const float* __restrict__ refp,
    const float* __restrict__ boff,  const float* __restrict__ battn,
    const float* __restrict__ bout,
    const short* __restrict__ WtH,   const short* __restrict__ WtL,
    const __half* __restrict__ v,    float* __restrict__ out)
{
    __shared__ __align__(16) char lds[54272];
    short*    sQh  = (short*)lds;                 // [16][264] bf16 hi (stage/E)
    short*    sQl  = (short*)(lds + 8448);        // [16][264] bf16 lo (stage/E)
    __half*   preT = (__half*)(lds + 33792);      // [16][264] fp16 sampled out
    __half*   sWh  = (__half*)(lds + 42240);      // [16][264] fp16 attn wts
    float*    sR   = (float*)(lds + 53760);       // [128] ref points

    const int t = threadIdx.x;
    const int n0 = blockIdx.x * 16;
    const int wv = t >> 6, lane = t & 63;
    const int mrow = lane & 15, kg = lane >> 4;
    float*    offW = (float*)lds + wv * 2112;     // per-wave [16][132] fp32 logits
    unsigned* sPIw = (unsigned*)(lds + 50688 + wv * 768);
    uint2*    sPWw = (uint2*)(lds + 50688 + wv * 768 + 256);

    // ---- Stage: query -> bf16 hi/lo LDS, ref points ----
    for (int k2 = 0; k2 < 16; ++k2) {
        float x = query[(n0 + k2) * 256 + t];
        short hi = bf16hi(x);
        sQh[k2 * 264 + t] = hi;
        sQl[k2 * 264 + t] = bf16hi(x - bf16f(hi));
    }
    if (t < 128) sR[t] = refp[n0 * 8 + t];
    __syncthreads();

    // ---- Phase B: logits via MFMA (hi/lo 3-pass for off AND attn) ----
    f32x4 accO[8], accA[4];
    {
        f32x4 z = {0.f, 0.f, 0.f, 0.f};
        #pragma unroll
        for (int j = 0; j < 8; ++j) accO[j] = z;
        #pragma unroll
        for (int j = 0; j < 4; ++j) accA[j] = z;
    }
    {
        const short* offH = WtH + (wv * 128 + mrow) * 256 + kg * 8;
        const short* offLo = WtL + (wv * 128 + mrow) * 256 + kg * 8;
        const short* attH = WtH + (512 + wv * 64 + mrow) * 256 + kg * 8;
        const short* attL = WtL + (512 + wv * 64 + mrow) * 256 + kg * 8;
        const int aoff = mrow * 264 + kg * 8;
        #pragma unroll
        for (int kk = 0; kk < 8; ++kk) {
            s16x8 ah = *(const s16x8*)(sQh + aoff + kk * 32);
            s16x8 al = *(const s16x8*)(sQl + aoff + kk * 32);
            #pragma unroll
            for (int j = 0; j < 8; ++j) {
                s16x8 bh = *(const s16x8*)(offH + j * 4096 + kk * 32);
                s16x8 bl = *(const s16x8*)(offLo + j * 4096 + kk * 32);
                accO[j] = MFMA16(ah, bh, accO[j]);
                accO[j] = MFMA16(al, bh, accO[j]);
                accO[j] = MFMA16(ah, bl, accO[j]);
            }
            #pragma unroll
            for (int ja = 0; ja < 4; ++ja) {
                s16x8 bh = *(const s16x8*)(attH + ja * 4096 + kk * 32);
                s16x8 bl = *(const s16x8*)(attL + ja * 4096 + kk * 32);
                accA[ja] = MFMA16(ah, bh, accA[ja]);
                accA[ja] = MFMA16(al, bh, accA[ja]);
                accA[ja] = MFMA16(ah, bl, accA[ja]);
            }
        }
    }
    // biases (D layout: col = mrow, rows = kg*4 + r)
    #pragma unroll
    for (int j = 0; j < 8; ++j) {
        float bb = boff[wv * 128 + j * 16 + mrow];
        #pragma unroll
        for (int r = 0; r < 4; ++r) accO[j][r] += bb;
    }
    #pragma unroll
    for (int ja = 0; ja < 4; ++ja) {
        float bb = battn[wv * 64 + ja * 16 + mrow];
        #pragma unroll
        for (int r = 0; r < 4; ++r) accA[ja][r] += bb;
    }
    __syncthreads();   // staged q dead everywhere; sQh/sQl arena becomes offW

    // ---- One-shot dump: wave wv -> its own offW block (verified D map) ----
    // offW[q][j*16 + mrow], q = kg*4 + r; within-wave col = hhL*64+l*16+p*2+xy
    #pragma unroll
    for (int j = 0; j < 8; ++j)
        #pragma unroll
        for (int r = 0; r < 4; ++r)
            offW[(kg * 4 + r) * 132 + j * 16 + mrow] = accO[j][r];
    // accO now dead -> frees 32 VGPRs for gather pipelining.

    // ---- Softmax over P=8 (8-lane groups), fp16 weights to sWh (own heads) ----
    #pragma unroll
    for (int ja = 0; ja < 4; ++ja) {
        int hh = 2 * wv + (ja >> 1);
        int l  = ((ja & 1) << 1) | (mrow >> 3);
        int p  = mrow & 7;
        #pragma unroll
        for (int r = 0; r < 4; ++r) {
            float x = accA[ja][r];
            float m = fmaxf(x, __shfl_xor(x, 1));
            m = fmaxf(m, __shfl_xor(m, 2));
            m = fmaxf(m, __shfl_xor(m, 4));
            float e = __expf(x - m);
            float s = e + __shfl_xor(e, 1);
            s += __shfl_xor(s, 2);
            s += __shfl_xor(s, 4);
            int q = kg * 4 + r;
            sWh[q * 264 + hh * 32 + l * 8 + p] = __float2half_rn(e / s);
        }
    }
    asm volatile("s_waitcnt lgkmcnt(0)" ::: "memory");
    __builtin_amdgcn_sched_barrier(0);

    // ---- Wave-autonomous chunk loop: one query per chunk, no block barriers ----
    // pack mapping: lane = hhL*32 + l*8 + p  (one record per lane)
    const int l_p = (lane >> 3) & 3, p_p = lane & 7, hhL_p = lane >> 5;
    const int Wl_p = 128 >> l_p;
    const float scl_p = 0.5f * (float)(Wl_p - 1);
    const int whCol = (2 * wv + hhL_p) * 32 + l_p * 8 + p_p;
    // sample mapping: sg = lane>>4 owns level sg; ch2 = lane&15 channel pair
    const int sg = kg, ch2 = mrow;
    const int Wl_s = 128 >> sg;
    const int HWs = Wl_s * Wl_s;
    const int dyoMul = Wl_s * 16;
    const int VBs = (sg == 0) ? VB[0] : (sg == 1) ? VB[1] : (sg == 2) ? VB[2] : VB[3];
    const __half2* vl0 = (const __half2*)(v + VBs + (2 * wv) * HWs * 32) + ch2;
    const __half2* vl1 = (const __half2*)(v + VBs + (2 * wv + 1) * HWs * 32) + ch2;

    for (int chunk = 0; chunk < 16; ++chunk) {
        // -- pack: each lane builds one record for (q=chunk, own head) --
        {
            float2 ll = *(const float2*)(offW + chunk * 132 + 2 * lane);
            float lx = ll.x, ly = ll.y;
            float w  = __half2float(sWh[chunk * 264 + whCol]);
            float rx = sR[chunk * 8 + l_p * 2], ry = sR[chunk * 8 + l_p * 2 + 1];
            float cx = rx + fast_tanh(lx) * 0.25f;
            float cy = ry + fast_tanh(ly) * 0.25f;
            float xx = (cx + 1.f) * scl_p, yy = (cy + 1.f) * scl_p;
            float x0f = floorf(xx), y0f = floorf(yy);
            float fx = xx - x0f, fy = yy - y0f;
            int x0 = (int)x0f, y0 = (int)y0f;
            int xc0 = min(max(x0, 0), Wl_p - 1);
            int xc1 = min(max(x0 + 1, 0), Wl_p - 1);
            int yc0 = min(max(y0, 0), Wl_p - 1);
            int yc1 = min(max(y0 + 1, 0), Wl_p - 1);
            bool bx0 = (x0 >= 0) & (x0 < Wl_p);
            bool bx1 = (x0 + 1 >= 0) & (x0 + 1 < Wl_p);
            bool by0 = (y0 >= 0) & (y0 < Wl_p);
            bool by1 = (y0 + 1 >= 0) & (y0 + 1 < Wl_p);
            float w00 = (bx0 && by0) ? (1.f - fx) * (1.f - fy) * w : 0.f;
            float w01 = (bx1 && by0) ? fx * (1.f - fy) * w : 0.f;
            float w10 = (bx0 && by1) ? (1.f - fx) * fy * w : 0.f;
            float w11 = (bx1 && by1) ? fx * fy * w : 0.f;
            unsigned pw = (unsigned)(yc0 * Wl_p + xc0)
                        | ((unsigned)(xc1 - xc0) << 14)
                        | ((unsigned)(yc1 - yc0) << 15);
            sPIw[lane] = pw;
            __half2 hA = __floats2half2_rn(w00, w01);
            __half2 hB = __floats2half2_rn(w10, w11);
            sPWw[lane] = make_uint2(*(unsigned*)&hA, *(unsigned*)&hB);
        }
        asm volatile("s_waitcnt lgkmcnt(0)" ::: "memory");
        __builtin_amdgcn_sched_barrier(0);

        // -- sample: sg owns level sg; iterate heads x points --
        float ax = 0.f, ay = 0.f;
        #pragma unroll
        for (int iter = 0; iter < 16; ++iter) {
            const int hhL = iter >> 3, p = iter & 7;
            const int rec = hhL * 32 + sg * 8 + p;
            unsigned pw = sPIw[rec];
            uint2 ww = sPWw[rec];
            const __half2* vl = hhL ? vl1 : vl0;
            int idx = pw & 0x3FFF;
            int dxo = ((pw >> 14) & 1) * 16;
            int dyo = ((pw >> 15) & 1) * dyoMul;
            const __half2* b00 = vl + idx * 16;
            float2 fa = __half22float2(*(__half2*)&ww.x);   // (w00, w01)
            float2 fb = __half22float2(*(__half2*)&ww.y);   // (w10, w11)
            float2 f00 = __half22float2(b00[0]);
            float2 f01 = __half22float2(b00[dxo]);
            float2 f10 = __half22float2(b00[dyo]);
            float2 f11 = __half22float2(b00[dxo + dyo]);
            ax += fa.x * f00.x + fa.y * f01.x + fb.x * f10.x + fb.y * f11.x;
            ay += fa.x * f00.y + fa.y * f01.y + fb.x * f10.y + fb.y * f11.y;
            if ((iter & 7) == 7) {
                // reduce over levels (sg groups) and store this head
                float sxv = ax + __shfl_xor(ax, 16); sxv += __shfl_xor(sxv, 32);
                float syv = ay + __shfl_xor(ay, 16); syv += __shfl_xor(syv, 32);
                if (sg == 0)
                    *(__half2*)(preT + chunk * 264 + (2 * wv + hhL) * 32 + ch2 * 2) =
                        __floats2half2_rn(sxv, syv);
                ax = 0.f; ay = 0.f;
            }
        }
        // drain record reads before next chunk's pack overwrites them
        asm volatile("s_waitcnt lgkmcnt(0)" ::: "memory");
        __builtin_amdgcn_sched_barrier(0);
    }
    __syncthreads();

    // ---- E-stage: preT (fp16) -> bf16 hi/lo, then MFMA out projection ----
    {
        int q = t & 15, seg = t >> 4;        // row q, cols [seg*16, seg*16+16)
        const __half2* src = (const __half2*)(preT + q * 264 + seg * 16);
        short* dh = sQh + q * 264 + seg * 16;
        short* dl = sQl + q * 264 + seg * 16;
        #pragma unroll
        for (int jj = 0; jj < 8; ++jj) {
            float2 f = __half22float2(src[jj]);
            short h0 = bf16hi(f.x), h1 = bf16hi(f.y);
            dh[2 * jj]     = h0;
            dh[2 * jj + 1] = h1;
            dl[2 * jj]     = bf16hi(f.x - bf16f(h0));
            dl[2 * jj + 1] = bf16hi(f.y - bf16f(h1));
        }
    }
    __syncthreads();

    {
        f32x4 accE[4];
        f32x4 z = {0.f, 0.f, 0.f, 0.f};
        #pragma unroll
        for (int e = 0; e < 4; ++e) accE[e] = z;
        const short* outH = WtH + (768 + wv * 64 + mrow) * 256 + kg * 8;
        const short* outL = WtL + (768 + wv * 64 + mrow) * 256 + kg * 8;
        const int aoff = mrow * 264 + kg * 8;
        #pragma unroll
        for (int kk = 0; kk < 8; ++kk) {
            s16x8 ah = *(const s16x8*)(sQh + aoff + kk * 32);
            s16x8 al = *(const s16x8*)(sQl + aoff + kk * 32);
            #pragma unroll
            for (int e = 0; e < 4; ++e) {
                s16x8 bh = *(const s16x8*)(outH + e * 4096 + kk * 32);
                s16x8 bl = *(const s16x8*)(outL + e * 4096 + kk * 32);
                accE[e] = MFMA16(ah, bh, accE[e]);
                accE[e] = MFMA16(al, bh, accE[e]);
                accE[e] = MFMA16(ah, bl, accE[e]);
            }
        }
        #pragma unroll
        for (int e = 0; e < 4; ++e) {
            int col = wv * 64 + e * 16 + mrow;
            float bb = bout[col];
            #pragma unroll
            for (int r = 0; r < 4; ++r)
                out[(n0 + kg * 4 + r) * 256 + col] = accE[e][r] + bb;
        }
    }
}

// ---------------------------------------------------------------------------
extern "C" void kernel_launch(void* const* d_in, const int* in_sizes, int n_in,
                              void* d_out, int out_size, void* d_ws, size_t ws_size,
                              hipStream_t stream) {
    const float* query = (const float*)d_in[0];
    const float* refp  = (const float*)d_in[1];
    const float* f0    = (const float*)d_in[2];
    const float* f1    = (const float*)d_in[3];
    const float* f2    = (const float*)d_in[4];
    const float* f3    = (const float*)d_in[5];
    const float* Woff  = (const float*)d_in[6];
    const float* boff  = (const float*)d_in[7];
    const float* Wattn = (const float*)d_in[8];
    const float* battn = (const float*)d_in[9];
    const float* Wval  = (const float*)d_in[10];
    const float* bval  = (const float*)d_in[11];
    const float* Wout  = (const float*)d_in[12];
    const float* bout  = (const float*)d_in[13];

    __half* v  = (__half*)d_ws;                              // 11,141,120 B
    short* WtH = (short*)((char*)d_ws + 11141120);           //    524,288 B
    short* WtL = WtH + 262144;                               //    524,288 B
    float* outp = (float*)d_out;

    prep_w<<<1024, 256, 0, stream>>>(Woff, Wattn, Wout, WtH, WtL);
    vproj_kernel<<<1360, 256, 0, stream>>>(f0, f1, f2, f3, Wval, bval, v);
    msda_kernel<<<2500, 256, 0, stream>>>(query, refp, boff, battn, bout,
                                          WtH, WtL, v, outp);
}

// Round 11
// 500.505 us; speedup vs baseline: 1.2942x; 1.1495x over previous
//
#include <hip/hip_runtime.h>
#include <hip/hip_fp16.h>
#include <math.h>

// Problem constants
#define NQ 40000

typedef short s16x8 __attribute__((ext_vector_type(8)));
typedef float f32x4 __attribute__((ext_vector_type(4)));

static constexpr int HLa[4] = {128, 64, 32, 16};
static constexpr int HWa[4] = {16384, 4096, 1024, 256};
// v bases (element units): level block is [HH][Hl][Wl][32]
static constexpr int VB[4] = {0, 4194304, 5242880, 5505024};
// total v elements = 5570560

__device__ __forceinline__ short bf16hi(float x) {
    union { float f; unsigned u; } v; v.f = x;
    unsigned r = v.u + 0x7FFFu + ((v.u >> 16) & 1u);
    return (short)(r >> 16);
}
__device__ __forceinline__ float bf16f(short s) {
    union { unsigned u; float f; } v; v.u = ((unsigned)(unsigned short)s) << 16;
    return v.f;
}
__device__ __forceinline__ float fast_tanh(float x) {
    float xc = fminf(fmaxf(x, -15.f), 15.f);
    float e = __expf(2.f * xc);
    return (e - 1.f) / (e + 1.f);
}
#define MFMA16(a, b, c) __builtin_amdgcn_mfma_f32_16x16x32_bf16(a, b, c, 0, 0, 0)

// ---------------------------------------------------------------------------
// Kernel 0: weight prep — transpose [C][N] -> [N][C], bf16 hi/lo split.
// rows: [0,512) = W_off cols, [512,768) = W_attn cols, [768,1024) = W_out cols
// ---------------------------------------------------------------------------
__global__ __launch_bounds__(256) void prep_w(
    const float* __restrict__ Woff, const float* __restrict__ Wattn,
    const float* __restrict__ Wout, short* __restrict__ WtH, short* __restrict__ WtL)
{
    int r = blockIdx.x, c = threadIdx.x;
    float x;
    if (r < 512)      x = Woff[c * 512 + r];
    else if (r < 768) x = Wattn[c * 256 + (r - 512)];
    else              x = Wout[c * 256 + (r - 768)];
    short hi = bf16hi(x);
    WtH[r * 256 + c] = hi;
    WtL[r * 256 + c] = bf16hi(x - bf16f(hi));
}

// ---------------------------------------------------------------------------
// Kernel 1: value projection -> fp16 table  v[l][hh][y][x][dd]
// ---------------------------------------------------------------------------
__global__ __launch_bounds__(256) void vproj_kernel(
    const float* __restrict__ f0, const float* __restrict__ f1,
    const float* __restrict__ f2, const float* __restrict__ f3,
    const float* __restrict__ Wv, const float* __restrict__ bv,
    __half* __restrict__ v)
{
    __shared__ float fT[256 * 16];  // [c][hw] 16KB

    int bid = blockIdx.x;
    const float* f;
    int base, HWl, hw0;
    if (bid < 1024)      { f = f0; base = VB[0]; HWl = 16384; hw0 = bid * 16; }
    else if (bid < 1280) { f = f1; base = VB[1]; HWl = 4096;  hw0 = (bid - 1024) * 16; }
    else if (bid < 1344) { f = f2; base = VB[2]; HWl = 1024;  hw0 = (bid - 1280) * 16; }
    else                 { f = f3; base = VB[3]; HWl = 256;   hw0 = (bid - 1344) * 16; }

    int t = threadIdx.x;
    for (int k = 0; k < 16; ++k) {
        int idx = k * 256 + t;
        int c = idx >> 4, j = idx & 15;
        fT[idx] = f[c * HWl + hw0 + j];
    }
    __syncthreads();

    int to4 = (t & 63) * 4;
    int hw4 = (t >> 6) * 4;

    float4 bv4 = *(const float4*)(bv + to4);
    float acc[4][4];
    #pragma unroll
    for (int i = 0; i < 4; ++i) {
        acc[i][0] = bv4.x; acc[i][1] = bv4.y; acc[i][2] = bv4.z; acc[i][3] = bv4.w;
    }

    #pragma unroll 4
    for (int c = 0; c < 256; ++c) {
        float4 w4 = *(const float4*)(Wv + c * 256 + to4);
        float4 fv = *(const float4*)(fT + c * 16 + hw4);
        float fa[4] = {fv.x, fv.y, fv.z, fv.w};
        float wa[4] = {w4.x, w4.y, w4.z, w4.w};
        #pragma unroll
        for (int i = 0; i < 4; ++i)
            #pragma unroll
            for (int j = 0; j < 4; ++j)
                acc[i][j] += fa[i] * wa[j];
    }

    int hh = to4 >> 5, dd4 = to4 & 31;
    #pragma unroll
    for (int i = 0; i < 4; ++i) {
        int hw = hw0 + hw4 + i;
        __half2 h0 = __floats2half2_rn(acc[i][0], acc[i][1]);
        __half2 h1 = __floats2half2_rn(acc[i][2], acc[i][3]);
        uint2 st = make_uint2(*(unsigned*)&h0, *(unsigned*)&h1);
        *(uint2*)(v + base + (hh * HWl + hw) * 32 + dd4) = st;
    }
}

// ---------------------------------------------------------------------------
// Kernel 2: MFMA logits -> 2 superpasses {per-wave 8-query logit dump ->
//           wave-autonomous per-query pack+gather} -> fp16 preT -> MFMA out.
// block = 256 threads (4 waves), 16 queries, 2500 blocks. LDS 37,376 B.
// LDS map: [0,16896) sQh/sQl (staging + E) aliased by per-wave offW
//          ([4 waves][8 q][132] fp32, wave-private, exactly 16896 B);
//          [16896,25344) preT; [25344,33792) sWh; [33792,36864) records;
//          [36864,37376) sR.  4 blocks/CU.
// ---------------------------------------------------------------------------
__global__ __launch_bounds__(256, 4) void msda_kernel(
    const float* __restrict__ query, const float* __restrict__ refp,
    const float* __restrict__ boff,  const float* __restrict__ battn,
    const float* __restrict__ bout,
    const short* __restrict__ WtH,   const short* __restrict__ WtL,
    const __half* __restrict__ v,    float* __restrict__ out)
{
    __shared__ __align__(16) char lds[37376];
    short*    sQh  = (short*)lds;                 // [16][264] bf16 hi (stage/E)
    short*    sQl  = (short*)(lds + 8448);        // [16][264] bf16 lo (stage/E)
    __half*   preT = (__half*)(lds + 16896);      // [16][264] fp16 sampled out
    __half*   sWh  = (__half*)(lds + 25344);      // [16][264] fp16 attn wts
    float*    sR   = (float*)(lds + 36864);       // [128] ref points

    const int t = threadIdx.x;
    const int n0 = blockIdx.x * 16;
    const int wv = t >> 6, lane = t & 63;
    const int mrow = lane & 15, kg = lane >> 4;
    float*    offW = (float*)lds + wv * 1056;     // per-wave [8][132] fp32 logits
    unsigned* sPIw = (unsigned*)(lds + 33792 + wv * 768);
    uint2*    sPWw = (uint2*)(lds + 33792 + wv * 768 + 256);

    // ---- Stage: query -> bf16 hi/lo LDS, ref points ----
    for (int k2 = 0; k2 < 16; ++k2) {
        float x = query[(n0 + k2) * 256 + t];
        short hi = bf16hi(x);
        sQh[k2 * 264 + t] = hi;
        sQl[k2 * 264 + t] = bf16hi(x - bf16f(hi));
    }
    if (t < 128) sR[t] = refp[n0 * 8 + t];
    __syncthreads();

    // ---- Phase B: logits via MFMA (hi/lo 3-pass for off AND attn) ----
    f32x4 accO[8], accA[4];
    {
        f32x4 z = {0.f, 0.f, 0.f, 0.f};
        #pragma unroll
        for (int j = 0; j < 8; ++j) accO[j] = z;
        #pragma unroll
        for (int j = 0; j < 4; ++j) accA[j] = z;
    }
    {
        const short* offH = WtH + (wv * 128 + mrow) * 256 + kg * 8;
        const short* offLo = WtL + (wv * 128 + mrow) * 256 + kg * 8;
        const short* attH = WtH + (512 + wv * 64 + mrow) * 256 + kg * 8;
        const short* attL = WtL + (512 + wv * 64 + mrow) * 256 + kg * 8;
        const int aoff = mrow * 264 + kg * 8;
        #pragma unroll
        for (int kk = 0; kk < 8; ++kk) {
            s16x8 ah = *(const s16x8*)(sQh + aoff + kk * 32);
            s16x8 al = *(const s16x8*)(sQl + aoff + kk * 32);
            #pragma unroll
            for (int j = 0; j < 8; ++j) {
                s16x8 bh = *(const s16x8*)(offH + j * 4096 + kk * 32);
                s16x8 bl = *(const s16x8*)(offLo + j * 4096 + kk * 32);
                accO[j] = MFMA16(ah, bh, accO[j]);
                accO[j] = MFMA16(al, bh, accO[j]);
                accO[j] = MFMA16(ah, bl, accO[j]);
            }
            #pragma unroll
            for (int ja = 0; ja < 4; ++ja) {
                s16x8 bh = *(const s16x8*)(attH + ja * 4096 + kk * 32);
                s16x8 bl = *(const s16x8*)(attL + ja * 4096 + kk * 32);
                accA[ja] = MFMA16(ah, bh, accA[ja]);
                accA[ja] = MFMA16(al, bh, accA[ja]);
                accA[ja] = MFMA16(ah, bl, accA[ja]);
            }
        }
    }
    // biases (D layout: col = mrow, rows = kg*4 + r)
    #pragma unroll
    for (int j = 0; j < 8; ++j) {
        float bb = boff[wv * 128 + j * 16 + mrow];
        #pragma unroll
        for (int r = 0; r < 4; ++r) accO[j][r] += bb;
    }
    #pragma unroll
    for (int ja = 0; ja < 4; ++ja) {
        float bb = battn[wv * 64 + ja * 16 + mrow];
        #pragma unroll
        for (int r = 0; r < 4; ++r) accA[ja][r] += bb;
    }

    // ---- Softmax over P=8 (8-lane groups), fp16 weights to sWh (own heads) ----
    #pragma unroll
    for (int ja = 0; ja < 4; ++ja) {
        int hh = 2 * wv + (ja >> 1);
        int l  = ((ja & 1) << 1) | (mrow >> 3);
        int p  = mrow & 7;
        #pragma unroll
        for (int r = 0; r < 4; ++r) {
            float x = accA[ja][r];
            float m = fmaxf(x, __shfl_xor(x, 1));
            m = fmaxf(m, __shfl_xor(m, 2));
            m = fmaxf(m, __shfl_xor(m, 4));
            float e = __expf(x - m);
            float s = e + __shfl_xor(e, 1);
            s += __shfl_xor(s, 2);
            s += __shfl_xor(s, 4);
            int q = kg * 4 + r;
            sWh[q * 264 + hh * 32 + l * 8 + p] = __float2half_rn(e / s);
        }
    }
    __syncthreads();   // all waves done reading staged q; arena becomes offW

    // ---- Chunk-loop setup ----
    // pack mapping: lane = hhL*32 + l*8 + p  (one record per lane)
    const int l_p = (lane >> 3) & 3, p_p = lane & 7, hhL_p = lane >> 5;
    const int Wl_p = 128 >> l_p;
    const float scl_p = 0.5f * (float)(Wl_p - 1);
    const int whCol = (2 * wv + hhL_p) * 32 + l_p * 8 + p_p;
    // sample mapping: sg = lane>>4 owns level sg; ch2 = lane&15 channel pair
    const int sg = kg, ch2 = mrow;
    const int Wl_s = 128 >> sg;
    const int HWs = Wl_s * Wl_s;
    const int dyoMul = Wl_s * 16;
    const int VBs = (sg == 0) ? VB[0] : (sg == 1) ? VB[1] : (sg == 2) ? VB[2] : VB[3];
    const __half2* vl0 = (const __half2*)(v + VBs + (2 * wv) * HWs * 32) + ch2;
    const __half2* vl1 = (const __half2*)(v + VBs + (2 * wv + 1) * HWs * 32) + ch2;

    // ---- 2 superpasses x 8 queries, wave-autonomous (no block barriers) ----
    for (int sp = 0; sp < 2; ++sp) {
        // dump: lanes holding q in [8sp, 8sp+8) write their accO rows
        if ((kg >> 1) == sp) {
            #pragma unroll
            for (int j = 0; j < 8; ++j)
                #pragma unroll
                for (int r = 0; r < 4; ++r)
                    offW[((kg & 1) * 4 + r) * 132 + j * 16 + mrow] = accO[j][r];
        }
        asm volatile("s_waitcnt lgkmcnt(0)" ::: "memory");
        __builtin_amdgcn_sched_barrier(0);

        for (int c8 = 0; c8 < 8; ++c8) {
            const int chunk = sp * 8 + c8;
            // -- pack: each lane builds one record for (q=chunk, own head) --
            {
                float2 ll = *(const float2*)(offW + c8 * 132 + 2 * lane);
                float lx = ll.x, ly = ll.y;
                float w  = __half2float(sWh[chunk * 264 + whCol]);
                float rx = sR[chunk * 8 + l_p * 2], ry = sR[chunk * 8 + l_p * 2 + 1];
                float cx = rx + fast_tanh(lx) * 0.25f;
                float cy = ry + fast_tanh(ly) * 0.25f;
                float xx = (cx + 1.f) * scl_p, yy = (cy + 1.f) * scl_p;
                float x0f = floorf(xx), y0f = floorf(yy);
                float fx = xx - x0f, fy = yy - y0f;
                int x0 = (int)x0f, y0 = (int)y0f;
                int xc0 = min(max(x0, 0), Wl_p - 1);
                int xc1 = min(max(x0 + 1, 0), Wl_p - 1);
                int yc0 = min(max(y0, 0), Wl_p - 1);
                int yc1 = min(max(y0 + 1, 0), Wl_p - 1);
                bool bx0 = (x0 >= 0) & (x0 < Wl_p);
                bool bx1 = (x0 + 1 >= 0) & (x0 + 1 < Wl_p);
                bool by0 = (y0 >= 0) & (y0 < Wl_p);
                bool by1 = (y0 + 1 >= 0) & (y0 + 1 < Wl_p);
                float w00 = (bx0 && by0) ? (1.f - fx) * (1.f - fy) * w : 0.f;
                float w01 = (bx1 && by0) ? fx * (1.f - fy) * w : 0.f;
                float w10 = (bx0 && by1) ? (1.f - fx) * fy * w : 0.f;
                float w11 = (bx1 && by1) ? fx * fy * w : 0.f;
                unsigned pw = (unsigned)(yc0 * Wl_p + xc0)
                            | ((unsigned)(xc1 - xc0) << 14)
                            | ((unsigned)(yc1 - yc0) << 15);
                sPIw[lane] = pw;
                __half2 hA = __floats2half2_rn(w00, w01);
                __half2 hB = __floats2half2_rn(w10, w11);
                sPWw[lane] = make_uint2(*(unsigned*)&hA, *(unsigned*)&hB);
            }
            asm volatile("s_waitcnt lgkmcnt(0)" ::: "memory");
            __builtin_amdgcn_sched_barrier(0);

            // -- sample: sg owns level sg; iterate heads x points --
            float ax = 0.f, ay = 0.f;
            #pragma unroll
            for (int iter = 0; iter < 16; ++iter) {
                const int hhL = iter >> 3, p = iter & 7;
                const int rec = hhL * 32 + sg * 8 + p;
                unsigned pw = sPIw[rec];
                uint2 ww = sPWw[rec];
                const __half2* vl = hhL ? vl1 : vl0;
                int idx = pw & 0x3FFF;
                int dxo = ((pw >> 14) & 1) * 16;
                int dyo = ((pw >> 15) & 1) * dyoMul;
                const __half2* b00 = vl + idx * 16;
                float2 fa = __half22float2(*(__half2*)&ww.x);   // (w00, w01)
                float2 fb = __half22float2(*(__half2*)&ww.y);   // (w10, w11)
                float2 f00 = __half22float2(b00[0]);
                float2 f01 = __half22float2(b00[dxo]);
                float2 f10 = __half22float2(b00[dyo]);
                float2 f11 = __half22float2(b00[dxo + dyo]);
                ax += fa.x * f00.x + fa.y * f01.x + fb.x * f10.x + fb.y * f11.x;
                ay += fa.x * f00.y + fa.y * f01.y + fb.x * f10.y + fb.y * f11.y;
                if ((iter & 7) == 7) {
                    // reduce over levels (sg groups) and store this head
                    float sxv = ax + __shfl_xor(ax, 16); sxv += __shfl_xor(sxv, 32);
                    float syv = ay + __shfl_xor(ay, 16); syv += __shfl_xor(syv, 32);
                    if (sg == 0)
                        *(__half2*)(preT + chunk * 264 + (2 * wv + hhL) * 32 + ch2 * 2) =
                            __floats2half2_rn(sxv, syv);
                    ax = 0.f; ay = 0.f;
                }
            }
            // drain record reads before next pack overwrites them
            asm volatile("s_waitcnt lgkmcnt(0)" ::: "memory");
            __builtin_amdgcn_sched_barrier(0);
        }
    }
    __syncthreads();

    // ---- E-stage: preT (fp16) -> bf16 hi/lo, then MFMA out projection ----
    {
        int q = t & 15, seg = t >> 4;        // row q, cols [seg*16, seg*16+16)
        const __half2* src = (const __half2*)(preT + q * 264 + seg * 16);
        short* dh = sQh + q * 264 + seg * 16;
        short* dl = sQl + q * 264 + seg * 16;
        #pragma unroll
        for (int jj = 0; jj < 8; ++jj) {
            float2 f = __half22float2(src[jj]);
            short h0 = bf16hi(f.x), h1 = bf16hi(f.y);
            dh[2 * jj]     = h0;
            dh[2 * jj + 1] = h1;
            dl[2 * jj]     = bf16hi(f.x - bf16f(h0));
            dl[2 * jj + 1] = bf16hi(f.y - bf16f(h1));
        }
    }
    __syncthreads();

    {
        f32x4 accE[4];
        f32x4 z = {0.f, 0.f, 0.f, 0.f};
        #pragma unroll
        for (int e = 0; e < 4; ++e) accE[e] = z;
        const short* outH = WtH + (768 + wv * 64 + mrow) * 256 + kg * 8;
        const short* outL = WtL + (768 + wv * 64 + mrow) * 256 + kg * 8;
        const int aoff = mrow * 264 + kg * 8;
        #pragma unroll
        for (int kk = 0; kk < 8; ++kk) {
            s16x8 ah = *(const s16x8*)(sQh + aoff + kk * 32);
            s16x8 al = *(const s16x8*)(sQl + aoff + kk * 32);
            #pragma unroll
            for (int e = 0; e < 4; ++e) {
                s16x8 bh = *(const s16x8*)(outH + e * 4096 + kk * 32);
                s16x8 bl = *(const s16x8*)(outL + e * 4096 + kk * 32);
                accE[e] = MFMA16(ah, bh, accE[e]);
                accE[e] = MFMA16(al, bh, accE[e]);
                accE[e] = MFMA16(ah, bl, accE[e]);
            }
        }
        #pragma unroll
        for (int e = 0; e < 4; ++e) {
            int col = wv * 64 + e * 16 + mrow;
            float bb = bout[col];
            #pragma unroll
            for (int r = 0; r < 4; ++r)
                out[(n0 + kg * 4 + r) * 256 + col] = accE[e][r] + bb;
        }
    }
}

// ---------------------------------------------------------------------------
extern "C" void kernel_launch(void* const* d_in, const int* in_sizes, int n_in,
                              void* d_out, int out_size, void* d_ws, size_t ws_size,
                              hipStream_t stream) {
    const float* query = (const float*)d_in[0];
    const float* refp  = (const float*)d_in[1];
    const float* f0    = (const float*)d_in[2];
    const float* f1    = (const float*)d_in[3];
    const float* f2    = (const float*)d_in[4];
    const float* f3    = (const float*)d_in[5];
    const float* Woff  = (const float*)d_in[6];
    const float* boff  = (const float*)d_in[7];
    const float* Wattn = (const float*)d_in[8];
    const float* battn = (const float*)d_in[9];
    const float* Wval  = (const float*)d_in[10];
    const float* bval  = (const float*)d_in[11];
    const float* Wout  = (const float*)d_in[12];
    const float* bout  = (const float*)d_in[13];

    __half* v  = (__half*)d_ws;                              // 11,141,120 B
    short* WtH = (short*)((char*)d_ws + 11141120);           //    524,288 B
    short* WtL = WtH + 262144;                               //    524,288 B
    float* outp = (float*)d_out;

    prep_w<<<1024, 256, 0, stream>>>(Woff, Wattn, Wout, WtH, WtL);
    vproj_kernel<<<1360, 256, 0, stream>>>(f0, f1, f2, f3, Wval, bval, v);
    msda_kernel<<<2500, 256, 0, stream>>>(query, refp, boff, battn, bout,
                                          WtH, WtL, v, outp);
}

// Round 12
// 499.468 us; speedup vs baseline: 1.2969x; 1.0021x over previous
//
#include <hip/hip_runtime.h>
#include <hip/hip_fp16.h>
#include <math.h>

// Problem constants
#define NQ 40000

typedef short s16x8 __attribute__((ext_vector_type(8)));
typedef float f32x4 __attribute__((ext_vector_type(4)));

static constexpr int HLa[4] = {128, 64, 32, 16};
static constexpr int HWa[4] = {16384, 4096, 1024, 256};
// v bases (element units): level block is [HH][Hl][Wl][32]
static constexpr int VB[4] = {0, 4194304, 5242880, 5505024};
// total v elements = 5570560

__device__ __forceinline__ short bf16hi(float x) {
    union { float f; unsigned u; } v; v.f = x;
    unsigned r = v.u + 0x7FFFu + ((v.u >> 16) & 1u);
    return (short)(r >> 16);
}
__device__ __forceinline__ float bf16f(short s) {
    union { unsigned u; float f; } v; v.u = ((unsigned)(unsigned short)s) << 16;
    return v.f;
}
__device__ __forceinline__ float fast_tanh(float x) {
    float xc = fminf(fmaxf(x, -15.f), 15.f);
    float e = __expf(2.f * xc);
    return (e - 1.f) / (e + 1.f);
}
#define MFMA16(a, b, c) __builtin_amdgcn_mfma_f32_16x16x32_bf16(a, b, c, 0, 0, 0)

// ---------------------------------------------------------------------------
// Kernel 0: weight prep — transpose [C][N] -> [N][C], bf16 hi/lo split.
// rows: [0,512) = W_off cols, [512,768) = W_attn cols, [768,1024) = W_out cols
// ---------------------------------------------------------------------------
__global__ __launch_bounds__(256) void prep_w(
    const float* __restrict__ Woff, const float* __restrict__ Wattn,
    const float* __restrict__ Wout, short* __restrict__ WtH, short* __restrict__ WtL)
{
    int r = blockIdx.x, c = threadIdx.x;
    float x;
    if (r < 512)      x = Woff[c * 512 + r];
    else if (r < 768) x = Wattn[c * 256 + (r - 512)];
    else              x = Wout[c * 256 + (r - 768)];
    short hi = bf16hi(x);
    WtH[r * 256 + c] = hi;
    WtL[r * 256 + c] = bf16hi(x - bf16f(hi));
}

// ---------------------------------------------------------------------------
// Kernel 1: value projection -> fp16 table  v[l][hh][y][x][dd]
// ---------------------------------------------------------------------------
__global__ __launch_bounds__(256) void vproj_kernel(
    const float* __restrict__ f0, const float* __restrict__ f1,
    const float* __restrict__ f2, const float* __restrict__ f3,
    const float* __restrict__ Wv, const float* __restrict__ bv,
    __half* __restrict__ v)
{
    __shared__ float fT[256 * 16];  // [c][hw] 16KB

    int bid = blockIdx.x;
    const float* f;
    int base, HWl, hw0;
    if (bid < 1024)      { f = f0; base = VB[0]; HWl = 16384; hw0 = bid * 16; }
    else if (bid < 1280) { f = f1; base = VB[1]; HWl = 4096;  hw0 = (bid - 1024) * 16; }
    else if (bid < 1344) { f = f2; base = VB[2]; HWl = 1024;  hw0 = (bid - 1280) * 16; }
    else                 { f = f3; base = VB[3]; HWl = 256;   hw0 = (bid - 1344) * 16; }

    int t = threadIdx.x;
    for (int k = 0; k < 16; ++k) {
        int idx = k * 256 + t;
        int c = idx >> 4, j = idx & 15;
        fT[idx] = f[c * HWl + hw0 + j];
    }
    __syncthreads();

    int to4 = (t & 63) * 4;
    int hw4 = (t >> 6) * 4;

    float4 bv4 = *(const float4*)(bv + to4);
    float acc[4][4];
    #pragma unroll
    for (int i = 0; i < 4; ++i) {
        acc[i][0] = bv4.x; acc[i][1] = bv4.y; acc[i][2] = bv4.z; acc[i][3] = bv4.w;
    }

    #pragma unroll 4
    for (int c = 0; c < 256; ++c) {
        float4 w4 = *(const float4*)(Wv + c * 256 + to4);
        float4 fv = *(const float4*)(fT + c * 16 + hw4);
        float fa[4] = {fv.x, fv.y, fv.z, fv.w};
        float wa[4] = {w4.x, w4.y, w4.z, w4.w};
        #pragma unroll
        for (int i = 0; i < 4; ++i)
            #pragma unroll
            for (int j = 0; j < 4; ++j)
                acc[i][j] += fa[i] * wa[j];
    }

    int hh = to4 >> 5, dd4 = to4 & 31;
    #pragma unroll
    for (int i = 0; i < 4; ++i) {
        int hw = hw0 + hw4 + i;
        __half2 h0 = __floats2half2_rn(acc[i][0], acc[i][1]);
        __half2 h1 = __floats2half2_rn(acc[i][2], acc[i][3]);
        uint2 st = make_uint2(*(unsigned*)&h0, *(unsigned*)&h1);
        *(uint2*)(v + base + (hh * HWl + hw) * 32 + dd4) = st;
    }
}

// ---------------------------------------------------------------------------
// Kernel 2: MFMA logits -> 2 superpasses {per-wave 8-query logit dump ->
//           wave-autonomous per-query pack+gather} -> fp16 preT -> MFMA out.
// block = 256 threads (4 waves), 16 queries, 2500 blocks. LDS 37,376 B.
// All chunk-loop LDS traffic is wave-private; same-wave DS ops execute in
// order, so NO explicit waits/fences — the compiler handles register deps
// and is free to software-pipeline pack(q+1) under sample(q)'s gathers.
// ---------------------------------------------------------------------------
__global__ __launch_bounds__(256, 4) void msda_kernel(
    const float* __restrict__ query, const float* __restrict__ refp,
    const float* __restrict__ boff,  const float* __restrict__ battn,
    const float* __restrict__ bout,
    const short* __restrict__ WtH,   const short* __restrict__ WtL,
    const __half* __restrict__ v,    float* __restrict__ out)
{
    __shared__ __align__(16) char lds[37376];
    short*    sQh  = (short*)lds;                 // [16][264] bf16 hi (stage/E)
    short*    sQl  = (short*)(lds + 8448);        // [16][264] bf16 lo (stage/E)
    __half*   preT = (__half*)(lds + 16896);      // [16][264] fp16 sampled out
    __half*   sWh  = (__half*)(lds + 25344);      // [16][264] fp16 attn wts
    float*    sR   = (float*)(lds + 36864);       // [128] ref points

    const int t = threadIdx.x;
    const int n0 = blockIdx.x * 16;
    const int wv = t >> 6, lane = t & 63;
    const int mrow = lane & 15, kg = lane >> 4;
    float*    offW = (float*)lds + wv * 1056;     // per-wave [8][132] fp32 logits
    unsigned* sPIw = (unsigned*)(lds + 33792 + wv * 768);
    uint2*    sPWw = (uint2*)(lds + 33792 + wv * 768 + 256);

    // ---- Stage: query -> bf16 hi/lo LDS, ref points ----
    for (int k2 = 0; k2 < 16; ++k2) {
        float x = query[(n0 + k2) * 256 + t];
        short hi = bf16hi(x);
        sQh[k2 * 264 + t] = hi;
        sQl[k2 * 264 + t] = bf16hi(x - bf16f(hi));
    }
    if (t < 128) sR[t] = refp[n0 * 8 + t];
    __syncthreads();

    // ---- Phase B: logits via MFMA (hi/lo 3-pass for off AND attn) ----
    f32x4 accO[8], accA[4];
    {
        f32x4 z = {0.f, 0.f, 0.f, 0.f};
        #pragma unroll
        for (int j = 0; j < 8; ++j) accO[j] = z;
        #pragma unroll
        for (int j = 0; j < 4; ++j) accA[j] = z;
    }
    {
        const short* offH = WtH + (wv * 128 + mrow) * 256 + kg * 8;
        const short* offLo = WtL + (wv * 128 + mrow) * 256 + kg * 8;
        const short* attH = WtH + (512 + wv * 64 + mrow) * 256 + kg * 8;
        const short* attL = WtL + (512 + wv * 64 + mrow) * 256 + kg * 8;
        const int aoff = mrow * 264 + kg * 8;
        #pragma unroll
        for (int kk = 0; kk < 8; ++kk) {
            s16x8 ah = *(const s16x8*)(sQh + aoff + kk * 32);
            s16x8 al = *(const s16x8*)(sQl + aoff + kk * 32);
            #pragma unroll
            for (int j = 0; j < 8; ++j) {
                s16x8 bh = *(const s16x8*)(offH + j * 4096 + kk * 32);
                s16x8 bl = *(const s16x8*)(offLo + j * 4096 + kk * 32);
                accO[j] = MFMA16(ah, bh, accO[j]);
                accO[j] = MFMA16(al, bh, accO[j]);
                accO[j] = MFMA16(ah, bl, accO[j]);
            }
            #pragma unroll
            for (int ja = 0; ja < 4; ++ja) {
                s16x8 bh = *(const s16x8*)(attH + ja * 4096 + kk * 32);
                s16x8 bl = *(const s16x8*)(attL + ja * 4096 + kk * 32);
                accA[ja] = MFMA16(ah, bh, accA[ja]);
                accA[ja] = MFMA16(al, bh, accA[ja]);
                accA[ja] = MFMA16(ah, bl, accA[ja]);
            }
        }
    }
    // biases (D layout: col = mrow, rows = kg*4 + r)
    #pragma unroll
    for (int j = 0; j < 8; ++j) {
        float bb = boff[wv * 128 + j * 16 + mrow];
        #pragma unroll
        for (int r = 0; r < 4; ++r) accO[j][r] += bb;
    }
    #pragma unroll
    for (int ja = 0; ja < 4; ++ja) {
        float bb = battn[wv * 64 + ja * 16 + mrow];
        #pragma unroll
        for (int r = 0; r < 4; ++r) accA[ja][r] += bb;
    }

    // ---- Softmax over P=8 (8-lane groups), fp16 weights to sWh (own heads) ----
    #pragma unroll
    for (int ja = 0; ja < 4; ++ja) {
        int hh = 2 * wv + (ja >> 1);
        int l  = ((ja & 1) << 1) | (mrow >> 3);
        int p  = mrow & 7;
        #pragma unroll
        for (int r = 0; r < 4; ++r) {
            float x = accA[ja][r];
            float m = fmaxf(x, __shfl_xor(x, 1));
            m = fmaxf(m, __shfl_xor(m, 2));
            m = fmaxf(m, __shfl_xor(m, 4));
            float e = __expf(x - m);
            float s = e + __shfl_xor(e, 1);
            s += __shfl_xor(s, 2);
            s += __shfl_xor(s, 4);
            int q = kg * 4 + r;
            sWh[q * 264 + hh * 32 + l * 8 + p] = __float2half_rn(e / s);
        }
    }
    __syncthreads();   // all waves done reading staged q; arena becomes offW

    // ---- Chunk-loop setup ----
    // pack mapping: lane = hhL*32 + l*8 + p  (one record per lane)
    const int l_p = (lane >> 3) & 3, p_p = lane & 7, hhL_p = lane >> 5;
    const int Wl_p = 128 >> l_p;
    const float scl_p = 0.5f * (float)(Wl_p - 1);
    const int whCol = (2 * wv + hhL_p) * 32 + l_p * 8 + p_p;
    // sample mapping: sg = lane>>4 owns level sg; ch2 = lane&15 channel pair
    const int sg = kg, ch2 = mrow;
    const int Wl_s = 128 >> sg;
    const int HWs = Wl_s * Wl_s;
    const int dyoMul = Wl_s * 16;
    const int VBs = (sg == 0) ? VB[0] : (sg == 1) ? VB[1] : (sg == 2) ? VB[2] : VB[3];
    const __half2* vl0 = (const __half2*)(v + VBs + (2 * wv) * HWs * 32) + ch2;
    const __half2* vl1 = (const __half2*)(v + VBs + (2 * wv + 1) * HWs * 32) + ch2;

    // ---- 2 superpasses x 8 queries, wave-autonomous (no block barriers,
    //      no explicit waits: same-wave DS ops are in-order) ----
    for (int sp = 0; sp < 2; ++sp) {
        // dump: lanes holding q in [8sp, 8sp+8) write their accO rows
        if ((kg >> 1) == sp) {
            #pragma unroll
            for (int j = 0; j < 8; ++j)
                #pragma unroll
                for (int r = 0; r < 4; ++r)
                    offW[((kg & 1) * 4 + r) * 132 + j * 16 + mrow] = accO[j][r];
        }

        for (int c8 = 0; c8 < 8; ++c8) {
            const int chunk = sp * 8 + c8;
            // -- pack: each lane builds one record for (q=chunk, own head) --
            {
                float2 ll = *(const float2*)(offW + c8 * 132 + 2 * lane);
                float lx = ll.x, ly = ll.y;
                float w  = __half2float(sWh[chunk * 264 + whCol]);
                float rx = sR[chunk * 8 + l_p * 2], ry = sR[chunk * 8 + l_p * 2 + 1];
                float cx = rx + fast_tanh(lx) * 0.25f;
                float cy = ry + fast_tanh(ly) * 0.25f;
                float xx = (cx + 1.f) * scl_p, yy = (cy + 1.f) * scl_p;
                float x0f = floorf(xx), y0f = floorf(yy);
                float fx = xx - x0f, fy = yy - y0f;
                int x0 = (int)x0f, y0 = (int)y0f;
                int xc0 = min(max(x0, 0), Wl_p - 1);
                int xc1 = min(max(x0 + 1, 0), Wl_p - 1);
                int yc0 = min(max(y0, 0), Wl_p - 1);
                int yc1 = min(max(y0 + 1, 0), Wl_p - 1);
                bool bx0 = (x0 >= 0) & (x0 < Wl_p);
                bool bx1 = (x0 + 1 >= 0) & (x0 + 1 < Wl_p);
                bool by0 = (y0 >= 0) & (y0 < Wl_p);
                bool by1 = (y0 + 1 >= 0) & (y0 + 1 < Wl_p);
                float w00 = (bx0 && by0) ? (1.f - fx) * (1.f - fy) * w : 0.f;
                float w01 = (bx1 && by0) ? fx * (1.f - fy) * w : 0.f;
                float w10 = (bx0 && by1) ? (1.f - fx) * fy * w : 0.f;
                float w11 = (bx1 && by1) ? fx * fy * w : 0.f;
                unsigned pw = (unsigned)(yc0 * Wl_p + xc0)
                            | ((unsigned)(xc1 - xc0) << 14)
                            | ((unsigned)(yc1 - yc0) << 15);
                sPIw[lane] = pw;
                __half2 hA = __floats2half2_rn(w00, w01);
                __half2 hB = __floats2half2_rn(w10, w11);
                sPWw[lane] = make_uint2(*(unsigned*)&hA, *(unsigned*)&hB);
            }

            // -- sample: sg owns level sg; iterate heads x points --
            float ax = 0.f, ay = 0.f;
            #pragma unroll
            for (int iter = 0; iter < 16; ++iter) {
                const int hhL = iter >> 3, p = iter & 7;
                const int rec = hhL * 32 + sg * 8 + p;
                unsigned pw = sPIw[rec];
                uint2 ww = sPWw[rec];
                const __half2* vl = hhL ? vl1 : vl0;
                int idx = pw & 0x3FFF;
                int dxo = ((pw >> 14) & 1) * 16;
                int dyo = ((pw >> 15) & 1) * dyoMul;
                const __half2* b00 = vl + idx * 16;
                float2 fa = __half22float2(*(__half2*)&ww.x);   // (w00, w01)
                float2 fb = __half22float2(*(__half2*)&ww.y);   // (w10, w11)
                float2 f00 = __half22float2(b00[0]);
                float2 f01 = __half22float2(b00[dxo]);
                float2 f10 = __half22float2(b00[dyo]);
                float2 f11 = __half22float2(b00[dxo + dyo]);
                ax += fa.x * f00.x + fa.y * f01.x + fb.x * f10.x + fb.y * f11.x;
                ay += fa.x * f00.y + fa.y * f01.y + fb.x * f10.y + fb.y * f11.y;
                if ((iter & 7) == 7) {
                    // reduce over levels (sg groups) and store this head
                    float sxv = ax + __shfl_xor(ax, 16); sxv += __shfl_xor(sxv, 32);
                    float syv = ay + __shfl_xor(ay, 16); syv += __shfl_xor(syv, 32);
                    if (sg == 0)
                        *(__half2*)(preT + chunk * 264 + (2 * wv + hhL) * 32 + ch2 * 2) =
                            __floats2half2_rn(sxv, syv);
                    ax = 0.f; ay = 0.f;
                }
            }
        }
    }
    __syncthreads();

    // ---- E-stage: preT (fp16) -> bf16 hi/lo, then MFMA out projection ----
    {
        int q = t & 15, seg = t >> 4;        // row q, cols [seg*16, seg*16+16)
        const __half2* src = (const __half2*)(preT + q * 264 + seg * 16);
        short* dh = sQh + q * 264 + seg * 16;
        short* dl = sQl + q * 264 + seg * 16;
        #pragma unroll
        for (int jj = 0; jj < 8; ++jj) {
            float2 f = __half22float2(src[jj]);
            short h0 = bf16hi(f.x), h1 = bf16hi(f.y);
            dh[2 * jj]     = h0;
            dh[2 * jj + 1] = h1;
            dl[2 * jj]     = bf16hi(f.x - bf16f(h0));
            dl[2 * jj + 1] = bf16hi(f.y - bf16f(h1));
        }
    }
    __syncthreads();

    {
        f32x4 accE[4];
        f32x4 z = {0.f, 0.f, 0.f, 0.f};
        #pragma unroll
        for (int e = 0; e < 4; ++e) accE[e] = z;
        const short* outH = WtH + (768 + wv * 64 + mrow) * 256 + kg * 8;
        const short* outL = WtL + (768 + wv * 64 + mrow) * 256 + kg * 8;
        const int aoff = mrow * 264 + kg * 8;
        #pragma unroll
        for (int kk = 0; kk < 8; ++kk) {
            s16x8 ah = *(const s16x8*)(sQh + aoff + kk * 32);
            s16x8 al = *(const s16x8*)(sQl + aoff + kk * 32);
            #pragma unroll
            for (int e = 0; e < 4; ++e) {
                s16x8 bh = *(const s16x8*)(outH + e * 4096 + kk * 32);
                s16x8 bl = *(const s16x8*)(outL + e * 4096 + kk * 32);
                accE[e] = MFMA16(ah, bh, accE[e]);
                accE[e] = MFMA16(al, bh, accE[e]);
                accE[e] = MFMA16(ah, bl, accE[e]);
            }
        }
        #pragma unroll
        for (int e = 0; e < 4; ++e) {
            int col = wv * 64 + e * 16 + mrow;
            float bb = bout[col];
            #pragma unroll
            for (int r = 0; r < 4; ++r)
                out[(n0 + kg * 4 + r) * 256 + col] = accE[e][r] + bb;
        }
    }
}

// ---------------------------------------------------------------------------
extern "C" void kernel_launch(void* const* d_in, const int* in_sizes, int n_in,
                              void* d_out, int out_size, void* d_ws, size_t ws_size,
                              hipStream_t stream) {
    const float* query = (const float*)d_in[0];
    const float* refp  = (const float*)d_in[1];
    const float* f0    = (const float*)d_in[2];
    const float* f1    = (const float*)d_in[3];
    const float* f2    = (const float*)d_in[4];
    const float* f3    = (const float*)d_in[5];
    const float* Woff  = (const float*)d_in[6];
    const float* boff  = (const float*)d_in[7];
    const float* Wattn = (const float*)d_in[8];
    const float* battn = (const float*)d_in[9];
    const float* Wval  = (const float*)d_in[10];
    const float* bval  = (const float*)d_in[11];
    const float* Wout  = (const float*)d_in[12];
    const float* bout  = (const float*)d_in[13];

    __half* v  = (__half*)d_ws;                              // 11,141,120 B
    short* WtH = (short*)((char*)d_ws + 11141120);           //    524,288 B
    short* WtL = WtH + 262144;                               //    524,288 B
    float* outp = (float*)d_out;

    prep_w<<<1024, 256, 0, stream>>>(Woff, Wattn, Wout, WtH, WtL);
    vproj_kernel<<<1360, 256, 0, stream>>>(f0, f1, f2, f3, Wval, bval, v);
    msda_kernel<<<2500, 256, 0, stream>>>(query, refp, boff, battn, bout,
                                          WtH, WtL, v, outp);
}

// Round 13
// 498.668 us; speedup vs baseline: 1.2990x; 1.0016x over previous
//
#include <hip/hip_runtime.h>
#include <hip/hip_fp16.h>
#include <math.h>

// Problem constants
#define NQ 40000

typedef short s16x8 __attribute__((ext_vector_type(8)));
typedef float f32x4 __attribute__((ext_vector_type(4)));

static constexpr int HLa[4] = {128, 64, 32, 16};
static constexpr int HWa[4] = {16384, 4096, 1024, 256};
// v bases (element units): level block is [HH][Hl][Wl][32]
static constexpr int VB[4] = {0, 4194304, 5242880, 5505024};
// total v elements = 5570560

__device__ __forceinline__ short bf16hi(float x) {
    union { float f; unsigned u; } v; v.f = x;
    unsigned r = v.u + 0x7FFFu + ((v.u >> 16) & 1u);
    return (short)(r >> 16);
}
__device__ __forceinline__ float bf16f(short s) {
    union { unsigned u; float f; } v; v.u = ((unsigned)(unsigned short)s) << 16;
    return v.f;
}
__device__ __forceinline__ float fast_tanh(float x) {
    float xc = fminf(fmaxf(x, -15.f), 15.f);
    float e = __expf(2.f * xc);
    return (e - 1.f) / (e + 1.f);
}
#define MFMA16(a, b, c) __builtin_amdgcn_mfma_f32_16x16x32_bf16(a, b, c, 0, 0, 0)

// ---------------------------------------------------------------------------
// Kernel 0: weight prep — transpose [C][N] -> [N][C], bf16 hi/lo split.
// rows: [0,512) = W_off cols, [512,768) = W_attn cols, [768,1024) = W_out cols
// ---------------------------------------------------------------------------
__global__ __launch_bounds__(256) void prep_w(
    const float* __restrict__ Woff, const float* __restrict__ Wattn,
    const float* __restrict__ Wout, short* __restrict__ WtH, short* __restrict__ WtL)
{
    int r = blockIdx.x, c = threadIdx.x;
    float x;
    if (r < 512)      x = Woff[c * 512 + r];
    else if (r < 768) x = Wattn[c * 256 + (r - 512)];
    else              x = Wout[c * 256 + (r - 768)];
    short hi = bf16hi(x);
    WtH[r * 256 + c] = hi;
    WtL[r * 256 + c] = bf16hi(x - bf16f(hi));
}

// ---------------------------------------------------------------------------
// Kernel 1: value projection -> fp16 table  v[l][hh][y][x][dd]
// ---------------------------------------------------------------------------
__global__ __launch_bounds__(256) void vproj_kernel(
    const float* __restrict__ f0, const float* __restrict__ f1,
    const float* __restrict__ f2, const float* __restrict__ f3,
    const float* __restrict__ Wv, const float* __restrict__ bv,
    __half* __restrict__ v)
{
    __shared__ float fT[256 * 16];  // [c][hw] 16KB

    int bid = blockIdx.x;
    const float* f;
    int base, HWl, hw0;
    if (bid < 1024)      { f = f0; base = VB[0]; HWl = 16384; hw0 = bid * 16; }
    else if (bid < 1280) { f = f1; base = VB[1]; HWl = 4096;  hw0 = (bid - 1024) * 16; }
    else if (bid < 1344) { f = f2; base = VB[2]; HWl = 1024;  hw0 = (bid - 1280) * 16; }
    else                 { f = f3; base = VB[3]; HWl = 256;   hw0 = (bid - 1344) * 16; }

    int t = threadIdx.x;
    for (int k = 0; k < 16; ++k) {
        int idx = k * 256 + t;
        int c = idx >> 4, j = idx & 15;
        fT[idx] = f[c * HWl + hw0 + j];
    }
    __syncthreads();

    int to4 = (t & 63) * 4;
    int hw4 = (t >> 6) * 4;

    float4 bv4 = *(const float4*)(bv + to4);
    float acc[4][4];
    #pragma unroll
    for (int i = 0; i < 4; ++i) {
        acc[i][0] = bv4.x; acc[i][1] = bv4.y; acc[i][2] = bv4.z; acc[i][3] = bv4.w;
    }

    #pragma unroll 4
    for (int c = 0; c < 256; ++c) {
        float4 w4 = *(const float4*)(Wv + c * 256 + to4);
        float4 fv = *(const float4*)(fT + c * 16 + hw4);
        float fa[4] = {fv.x, fv.y, fv.z, fv.w};
        float wa[4] = {w4.x, w4.y, w4.z, w4.w};
        #pragma unroll
        for (int i = 0; i < 4; ++i)
            #pragma unroll
            for (int j = 0; j < 4; ++j)
                acc[i][j] += fa[i] * wa[j];
    }

    int hh = to4 >> 5, dd4 = to4 & 31;
    #pragma unroll
    for (int i = 0; i < 4; ++i) {
        int hw = hw0 + hw4 + i;
        __half2 h0 = __floats2half2_rn(acc[i][0], acc[i][1]);
        __half2 h1 = __floats2half2_rn(acc[i][2], acc[i][3]);
        uint2 st = make_uint2(*(unsigned*)&h0, *(unsigned*)&h1);
        *(uint2*)(v + base + (hh * HWl + hw) * 32 + dd4) = st;
    }
}

// ---------------------------------------------------------------------------
// Kernel 2: MFMA logits -> 2 superpasses {per-wave 8-query logit dump ->
//           wave-autonomous per-query pack+gather} -> fp16 preT -> MFMA out.
// block = 256 threads (4 waves), 16 queries, 2500 blocks. LDS 28,928 B
// -> 5 blocks/CU.  preT ALIASES sWh: for chunk q each wave reads its own
// 64 attn-wt columns (pack) BEFORE writing the same 64 columns (preT) —
// same-wave DS ops are in-order; other waves' columns disjoint; E-stage
// reads after __syncthreads.
// ---------------------------------------------------------------------------
__global__ __launch_bounds__(256, 4) void msda_kernel(
    const float* __restrict__ query, const float* __restrict__ refp,
    const float* __restrict__ boff,  const float* __restrict__ battn,
    const float* __restrict__ bout,
    const short* __restrict__ WtH,   const short* __restrict__ WtL,
    const __half* __restrict__ v,    float* __restrict__ out)
{
    __shared__ __align__(16) char lds[28928];
    short*    sQh  = (short*)lds;                 // [16][264] bf16 hi (stage/E)
    short*    sQl  = (short*)(lds + 8448);        // [16][264] bf16 lo (stage/E)
    __half*   sWh  = (__half*)(lds + 16896);      // [16][264] attn wts -> preT (aliased)
    float*    sR   = (float*)(lds + 28416);       // [128] ref points

    const int t = threadIdx.x;
    const int n0 = blockIdx.x * 16;
    const int wv = t >> 6, lane = t & 63;
    const int mrow = lane & 15, kg = lane >> 4;
    float*    offW = (float*)lds + wv * 1056;     // per-wave [8][132] fp32 logits
    unsigned* sPIw = (unsigned*)(lds + 25344 + wv * 768);
    uint2*    sPWw = (uint2*)(lds + 25344 + wv * 768 + 256);
    __half*   preT = sWh;                          // alias (audited above)

    // ---- Stage: query -> bf16 hi/lo LDS, ref points ----
    for (int k2 = 0; k2 < 16; ++k2) {
        float x = query[(n0 + k2) * 256 + t];
        short hi = bf16hi(x);
        sQh[k2 * 264 + t] = hi;
        sQl[k2 * 264 + t] = bf16hi(x - bf16f(hi));
    }
    if (t < 128) sR[t] = refp[n0 * 8 + t];
    __syncthreads();

    // ---- Phase B: logits via MFMA (hi/lo 3-pass for off AND attn) ----
    f32x4 accO[8], accA[4];
    {
        f32x4 z = {0.f, 0.f, 0.f, 0.f};
        #pragma unroll
        for (int j = 0; j < 8; ++j) accO[j] = z;
        #pragma unroll
        for (int j = 0; j < 4; ++j) accA[j] = z;
    }
    {
        const short* offH = WtH + (wv * 128 + mrow) * 256 + kg * 8;
        const short* offLo = WtL + (wv * 128 + mrow) * 256 + kg * 8;
        const short* attH = WtH + (512 + wv * 64 + mrow) * 256 + kg * 8;
        const short* attL = WtL + (512 + wv * 64 + mrow) * 256 + kg * 8;
        const int aoff = mrow * 264 + kg * 8;
        #pragma unroll
        for (int kk = 0; kk < 8; ++kk) {
            s16x8 ah = *(const s16x8*)(sQh + aoff + kk * 32);
            s16x8 al = *(const s16x8*)(sQl + aoff + kk * 32);
            #pragma unroll
            for (int j = 0; j < 8; ++j) {
                s16x8 bh = *(const s16x8*)(offH + j * 4096 + kk * 32);
                s16x8 bl = *(const s16x8*)(offLo + j * 4096 + kk * 32);
                accO[j] = MFMA16(ah, bh, accO[j]);
                accO[j] = MFMA16(al, bh, accO[j]);
                accO[j] = MFMA16(ah, bl, accO[j]);
            }
            #pragma unroll
            for (int ja = 0; ja < 4; ++ja) {
                s16x8 bh = *(const s16x8*)(attH + ja * 4096 + kk * 32);
                s16x8 bl = *(const s16x8*)(attL + ja * 4096 + kk * 32);
                accA[ja] = MFMA16(ah, bh, accA[ja]);
                accA[ja] = MFMA16(al, bh, accA[ja]);
                accA[ja] = MFMA16(ah, bl, accA[ja]);
            }
        }
    }
    // biases (D layout: col = mrow, rows = kg*4 + r)
    #pragma unroll
    for (int j = 0; j < 8; ++j) {
        float bb = boff[wv * 128 + j * 16 + mrow];
        #pragma unroll
        for (int r = 0; r < 4; ++r) accO[j][r] += bb;
    }
    #pragma unroll
    for (int ja = 0; ja < 4; ++ja) {
        float bb = battn[wv * 64 + ja * 16 + mrow];
        #pragma unroll
        for (int r = 0; r < 4; ++r) accA[ja][r] += bb;
    }

    // ---- Softmax over P=8 (8-lane groups), fp16 weights to sWh (own heads) ----
    #pragma unroll
    for (int ja = 0; ja < 4; ++ja) {
        int hh = 2 * wv + (ja >> 1);
        int l  = ((ja & 1) << 1) | (mrow >> 3);
        int p  = mrow & 7;
        #pragma unroll
        for (int r = 0; r < 4; ++r) {
            float x = accA[ja][r];
            float m = fmaxf(x, __shfl_xor(x, 1));
            m = fmaxf(m, __shfl_xor(m, 2));
            m = fmaxf(m, __shfl_xor(m, 4));
            float e = __expf(x - m);
            float s = e + __shfl_xor(e, 1);
            s += __shfl_xor(s, 2);
            s += __shfl_xor(s, 4);
            int q = kg * 4 + r;
            sWh[q * 264 + hh * 32 + l * 8 + p] = __float2half_rn(e / s);
        }
    }
    __syncthreads();   // all waves done reading staged q; arena becomes offW

    // ---- Chunk-loop setup ----
    // pack mapping: lane = hhL*32 + l*8 + p  (one record per lane)
    const int l_p = (lane >> 3) & 3, p_p = lane & 7, hhL_p = lane >> 5;
    const int Wl_p = 128 >> l_p;
    const float scl_p = 0.5f * (float)(Wl_p - 1);
    const int whCol = (2 * wv + hhL_p) * 32 + l_p * 8 + p_p;
    // sample mapping: sg = lane>>4 owns level sg; ch2 = lane&15 channel pair
    const int sg = kg, ch2 = mrow;
    const int Wl_s = 128 >> sg;
    const int HWs = Wl_s * Wl_s;
    const int dyoMul = Wl_s * 16;
    const int VBs = (sg == 0) ? VB[0] : (sg == 1) ? VB[1] : (sg == 2) ? VB[2] : VB[3];
    const __half2* vl0 = (const __half2*)(v + VBs + (2 * wv) * HWs * 32) + ch2;
    const __half2* vl1 = (const __half2*)(v + VBs + (2 * wv + 1) * HWs * 32) + ch2;

    // ---- 2 superpasses x 8 queries, wave-autonomous ----
    for (int sp = 0; sp < 2; ++sp) {
        // dump: lanes holding q in [8sp, 8sp+8) write their accO rows
        if ((kg >> 1) == sp) {
            #pragma unroll
            for (int j = 0; j < 8; ++j)
                #pragma unroll
                for (int r = 0; r < 4; ++r)
                    offW[((kg & 1) * 4 + r) * 132 + j * 16 + mrow] = accO[j][r];
        }

        for (int c8 = 0; c8 < 8; ++c8) {
            const int chunk = sp * 8 + c8;
            // -- pack: each lane builds one record for (q=chunk, own head) --
            {
                float2 ll = *(const float2*)(offW + c8 * 132 + 2 * lane);
                float lx = ll.x, ly = ll.y;
                float w  = __half2float(sWh[chunk * 264 + whCol]);
                float rx = sR[chunk * 8 + l_p * 2], ry = sR[chunk * 8 + l_p * 2 + 1];
                float cx = rx + fast_tanh(lx) * 0.25f;
                float cy = ry + fast_tanh(ly) * 0.25f;
                float xx = (cx + 1.f) * scl_p, yy = (cy + 1.f) * scl_p;
                float x0f = floorf(xx), y0f = floorf(yy);
                float fx = xx - x0f, fy = yy - y0f;
                int x0 = (int)x0f, y0 = (int)y0f;
                int xc0 = min(max(x0, 0), Wl_p - 1);
                int xc1 = min(max(x0 + 1, 0), Wl_p - 1);
                int yc0 = min(max(y0, 0), Wl_p - 1);
                int yc1 = min(max(y0 + 1, 0), Wl_p - 1);
                bool bx0 = (x0 >= 0) & (x0 < Wl_p);
                bool bx1 = (x0 + 1 >= 0) & (x0 + 1 < Wl_p);
                bool by0 = (y0 >= 0) & (y0 < Wl_p);
                bool by1 = (y0 + 1 >= 0) & (y0 + 1 < Wl_p);
                float w00 = (bx0 && by0) ? (1.f - fx) * (1.f - fy) * w : 0.f;
                float w01 = (bx1 && by0) ? fx * (1.f - fy) * w : 0.f;
                float w10 = (bx0 && by1) ? (1.f - fx) * fy * w : 0.f;
                float w11 = (bx1 && by1) ? fx * fy * w : 0.f;
                unsigned pw = (unsigned)(yc0 * Wl_p + xc0)
                            | ((unsigned)(xc1 - xc0) << 14)
                            | ((unsigned)(yc1 - yc0) << 15);
                sPIw[lane] = pw;
                __half2 hA = __floats2half2_rn(w00, w01);
                __half2 hB = __floats2half2_rn(w10, w11);
                sPWw[lane] = make_uint2(*(unsigned*)&hA, *(unsigned*)&hB);
            }

            // -- sample: sg owns level sg; iterate heads x points --
            float ax = 0.f, ay = 0.f;
            #pragma unroll
            for (int iter = 0; iter < 16; ++iter) {
                const int hhL = iter >> 3, p = iter & 7;
                const int rec = hhL * 32 + sg * 8 + p;
                unsigned pw = sPIw[rec];
                uint2 ww = sPWw[rec];
                const __half2* vl = hhL ? vl1 : vl0;
                int idx = pw & 0x3FFF;
                int dxo = ((pw >> 14) & 1) * 16;
                int dyo = ((pw >> 15) & 1) * dyoMul;
                const __half2* b00 = vl + idx * 16;
                float2 fa = __half22float2(*(__half2*)&ww.x);   // (w00, w01)
                float2 fb = __half22float2(*(__half2*)&ww.y);   // (w10, w11)
                float2 f00 = __half22float2(b00[0]);
                float2 f01 = __half22float2(b00[dxo]);
                float2 f10 = __half22float2(b00[dyo]);
                float2 f11 = __half22float2(b00[dxo + dyo]);
                ax += fa.x * f00.x + fa.y * f01.x + fb.x * f10.x + fb.y * f11.x;
                ay += fa.x * f00.y + fa.y * f01.y + fb.x * f10.y + fb.y * f11.y;
                if ((iter & 7) == 7) {
                    // reduce over levels (sg groups) and store this head
                    float sxv = ax + __shfl_xor(ax, 16); sxv += __shfl_xor(sxv, 32);
                    float syv = ay + __shfl_xor(ay, 16); syv += __shfl_xor(syv, 32);
                    if (sg == 0)
                        *(__half2*)(preT + chunk * 264 + (2 * wv + hhL) * 32 + ch2 * 2) =
                            __floats2half2_rn(sxv, syv);
                    ax = 0.f; ay = 0.f;
                }
            }
        }
    }
    __syncthreads();

    // ---- E-stage: preT (fp16) -> bf16 hi/lo, then MFMA out projection ----
    {
        int q = t & 15, seg = t >> 4;        // row q, cols [seg*16, seg*16+16)
        const __half2* src = (const __half2*)(preT + q * 264 + seg * 16);
        short* dh = sQh + q * 264 + seg * 16;
        short* dl = sQl + q * 264 + seg * 16;
        #pragma unroll
        for (int jj = 0; jj < 8; ++jj) {
            float2 f = __half22float2(src[jj]);
            short h0 = bf16hi(f.x), h1 = bf16hi(f.y);
            dh[2 * jj]     = h0;
            dh[2 * jj + 1] = h1;
            dl[2 * jj]     = bf16hi(f.x - bf16f(h0));
            dl[2 * jj + 1] = bf16hi(f.y - bf16f(h1));
        }
    }
    __syncthreads();

    {
        f32x4 accE[4];
        f32x4 z = {0.f, 0.f, 0.f, 0.f};
        #pragma unroll
        for (int e = 0; e < 4; ++e) accE[e] = z;
        const short* outH = WtH + (768 + wv * 64 + mrow) * 256 + kg * 8;
        const short* outL = WtL + (768 + wv * 64 + mrow) * 256 + kg * 8;
        const int aoff = mrow * 264 + kg * 8;
        #pragma unroll
        for (int kk = 0; kk < 8; ++kk) {
            s16x8 ah = *(const s16x8*)(sQh + aoff + kk * 32);
            s16x8 al = *(const s16x8*)(sQl + aoff + kk * 32);
            #pragma unroll
            for (int e = 0; e < 4; ++e) {
                s16x8 bh = *(const s16x8*)(outH + e * 4096 + kk * 32);
                s16x8 bl = *(const s16x8*)(outL + e * 4096 + kk * 32);
                accE[e] = MFMA16(ah, bh, accE[e]);
                accE[e] = MFMA16(al, bh, accE[e]);
                accE[e] = MFMA16(ah, bl, accE[e]);
            }
        }
        #pragma unroll
        for (int e = 0; e < 4; ++e) {
            int col = wv * 64 + e * 16 + mrow;
            float bb = bout[col];
            #pragma unroll
            for (int r = 0; r < 4; ++r)
                out[(n0 + kg * 4 + r) * 256 + col] = accE[e][r] + bb;
        }
    }
}

// ---------------------------------------------------------------------------
extern "C" void kernel_launch(void* const* d_in, const int* in_sizes, int n_in,
                              void* d_out, int out_size, void* d_ws, size_t ws_size,
                              hipStream_t stream) {
    const float* query = (const float*)d_in[0];
    const float* refp  = (const float*)d_in[1];
    const float* f0    = (const float*)d_in[2];
    const float* f1    = (const float*)d_in[3];
    const float* f2    = (const float*)d_in[4];
    const float* f3    = (const float*)d_in[5];
    const float* Woff  = (const float*)d_in[6];
    const float* boff  = (const float*)d_in[7];
    const float* Wattn = (const float*)d_in[8];
    const float* battn = (const float*)d_in[9];
    const float* Wval  = (const float*)d_in[10];
    const float* bval  = (const float*)d_in[11];
    const float* Wout  = (const float*)d_in[12];
    const float* bout  = (const float*)d_in[13];

    __half* v  = (__half*)d_ws;                              // 11,141,120 B
    short* WtH = (short*)((char*)d_ws + 11141120);           //    524,288 B
    short* WtL = WtH + 262144;                               //    524,288 B
    float* outp = (float*)d_out;

    prep_w<<<1024, 256, 0, stream>>>(Woff, Wattn, Wout, WtH, WtL);
    vproj_kernel<<<1360, 256, 0, stream>>>(f0, f1, f2, f3, Wval, bval, v);
    msda_kernel<<<2500, 256, 0, stream>>>(query, refp, boff, battn, bout,
                                          WtH, WtL, v, outp);
}

// Round 14
// 498.289 us; speedup vs baseline: 1.3000x; 1.0008x over previous
//
#include <hip/hip_runtime.h>
#include <hip/hip_fp16.h>
#include <math.h>

// Problem constants
#define NQ 40000

typedef short s16x8 __attribute__((ext_vector_type(8)));
typedef float f32x4 __attribute__((ext_vector_type(4)));

static constexpr int HLa[4] = {128, 64, 32, 16};
static constexpr int HWa[4] = {16384, 4096, 1024, 256};
// v bases (element units): level block is [HH][Hl][Wl][32]
static constexpr int VB[4] = {0, 4194304, 5242880, 5505024};
// total v elements = 5570560

__device__ __forceinline__ short bf16hi(float x) {
    union { float f; unsigned u; } v; v.f = x;
    unsigned r = v.u + 0x7FFFu + ((v.u >> 16) & 1u);
    return (short)(r >> 16);
}
__device__ __forceinline__ float bf16f(short s) {
    union { unsigned u; float f; } v; v.u = ((unsigned)(unsigned short)s) << 16;
    return v.f;
}
__device__ __forceinline__ float fast_tanh(float x) {
    float xc = fminf(fmaxf(x, -15.f), 15.f);
    float e = __expf(2.f * xc);
    return (e - 1.f) / (e + 1.f);
}
#define MFMA16(a, b, c) __builtin_amdgcn_mfma_f32_16x16x32_bf16(a, b, c, 0, 0, 0)

// ---------------------------------------------------------------------------
// Kernel 0: weight prep — transpose [C][N] -> [N][C], bf16 hi/lo split.
// rows: [0,512) = W_off cols, [512,768) = W_attn cols, [768,1024) = W_out cols
// ---------------------------------------------------------------------------
__global__ __launch_bounds__(256) void prep_w(
    const float* __restrict__ Woff, const float* __restrict__ Wattn,
    const float* __restrict__ Wout, short* __restrict__ WtH, short* __restrict__ WtL)
{
    int r = blockIdx.x, c = threadIdx.x;
    float x;
    if (r < 512)      x = Woff[c * 512 + r];
    else if (r < 768) x = Wattn[c * 256 + (r - 512)];
    else              x = Wout[c * 256 + (r - 768)];
    short hi = bf16hi(x);
    WtH[r * 256 + c] = hi;
    WtL[r * 256 + c] = bf16hi(x - bf16f(hi));
}

// ---------------------------------------------------------------------------
// Kernel 1: value projection -> fp16 table  v[l][hh][y][x][dd]
// ---------------------------------------------------------------------------
__global__ __launch_bounds__(256) void vproj_kernel(
    const float* __restrict__ f0, const float* __restrict__ f1,
    const float* __restrict__ f2, const float* __restrict__ f3,
    const float* __restrict__ Wv, const float* __restrict__ bv,
    __half* __restrict__ v)
{
    __shared__ float fT[256 * 16];  // [c][hw] 16KB

    int bid = blockIdx.x;
    const float* f;
    int base, HWl, hw0;
    if (bid < 1024)      { f = f0; base = VB[0]; HWl = 16384; hw0 = bid * 16; }
    else if (bid < 1280) { f = f1; base = VB[1]; HWl = 4096;  hw0 = (bid - 1024) * 16; }
    else if (bid < 1344) { f = f2; base = VB[2]; HWl = 1024;  hw0 = (bid - 1280) * 16; }
    else                 { f = f3; base = VB[3]; HWl = 256;   hw0 = (bid - 1344) * 16; }

    int t = threadIdx.x;
    for (int k = 0; k < 16; ++k) {
        int idx = k * 256 + t;
        int c = idx >> 4, j = idx & 15;
        fT[idx] = f[c * HWl + hw0 + j];
    }
    __syncthreads();

    int to4 = (t & 63) * 4;
    int hw4 = (t >> 6) * 4;

    float4 bv4 = *(const float4*)(bv + to4);
    float acc[4][4];
    #pragma unroll
    for (int i = 0; i < 4; ++i) {
        acc[i][0] = bv4.x; acc[i][1] = bv4.y; acc[i][2] = bv4.z; acc[i][3] = bv4.w;
    }

    #pragma unroll 4
    for (int c = 0; c < 256; ++c) {
        float4 w4 = *(const float4*)(Wv + c * 256 + to4);
        float4 fv = *(const float4*)(fT + c * 16 + hw4);
        float fa[4] = {fv.x, fv.y, fv.z, fv.w};
        float wa[4] = {w4.x, w4.y, w4.z, w4.w};
        #pragma unroll
        for (int i = 0; i < 4; ++i)
            #pragma unroll
            for (int j = 0; j < 4; ++j)
                acc[i][j] += fa[i] * wa[j];
    }

    int hh = to4 >> 5, dd4 = to4 & 31;
    #pragma unroll
    for (int i = 0; i < 4; ++i) {
        int hw = hw0 + hw4 + i;
        __half2 h0 = __floats2half2_rn(acc[i][0], acc[i][1]);
        __half2 h1 = __floats2half2_rn(acc[i][2], acc[i][3]);
        uint2 st = make_uint2(*(unsigned*)&h0, *(unsigned*)&h1);
        *(uint2*)(v + base + (hh * HWl + hw) * 32 + dd4) = st;
    }
}

// pack one record per lane for query CHUNK into buffers DPI/DPW
#define PACK_REC(CHUNK, DPI, DPW) do {                                        \
    float2 ll = *(const float2*)(offW + ((CHUNK) & 7) * 132 + 2 * lane);      \
    float lx = ll.x, ly = ll.y;                                               \
    float w  = __half2float(sWh[(CHUNK) * 264 + whCol]);                      \
    float rx = sR[(CHUNK) * 8 + l_p * 2], ry = sR[(CHUNK) * 8 + l_p * 2 + 1]; \
    float cx = rx + fast_tanh(lx) * 0.25f;                                    \
    float cy = ry + fast_tanh(ly) * 0.25f;                                    \
    float xx = (cx + 1.f) * scl_p, yy = (cy + 1.f) * scl_p;                   \
    float x0f = floorf(xx), y0f = floorf(yy);                                 \
    float fx = xx - x0f, fy = yy - y0f;                                       \
    int x0 = (int)x0f, y0 = (int)y0f;                                         \
    int xc0 = min(max(x0, 0), Wl_p - 1);                                      \
    int xc1 = min(max(x0 + 1, 0), Wl_p - 1);                                  \
    int yc0 = min(max(y0, 0), Wl_p - 1);                                      \
    int yc1 = min(max(y0 + 1, 0), Wl_p - 1);                                  \
    bool bx0 = (x0 >= 0) & (x0 < Wl_p);                                       \
    bool bx1 = (x0 + 1 >= 0) & (x0 + 1 < Wl_p);                               \
    bool by0 = (y0 >= 0) & (y0 < Wl_p);                                       \
    bool by1 = (y0 + 1 >= 0) & (y0 + 1 < Wl_p);                               \
    float w00 = (bx0 && by0) ? (1.f - fx) * (1.f - fy) * w : 0.f;             \
    float w01 = (bx1 && by0) ? fx * (1.f - fy) * w : 0.f;                     \
    float w10 = (bx0 && by1) ? (1.f - fx) * fy * w : 0.f;                     \
    float w11 = (bx1 && by1) ? fx * fy * w : 0.f;                             \
    unsigned pw = (unsigned)(yc0 * Wl_p + xc0)                                \
                | ((unsigned)(xc1 - xc0) << 14)                               \
                | ((unsigned)(yc1 - yc0) << 15);                              \
    (DPI)[lane] = pw;                                                         \
    __half2 hA = __floats2half2_rn(w00, w01);                                 \
    __half2 hB = __floats2half2_rn(w10, w11);                                 \
    (DPW)[lane] = make_uint2(*(unsigned*)&hA, *(unsigned*)&hB);               \
} while (0)

// ---------------------------------------------------------------------------
// Kernel 2: MFMA logits -> 2 superpasses {per-wave 8-query logit dump ->
//           wave-autonomous SOFTWARE-PIPELINED pack/gather (ping-pong record
//           buffers, issue-early/blend-late)} -> fp16 preT -> MFMA out.
// block = 256 threads (4 waves), 16 queries, 2500 blocks. LDS 32,000 B.
// ---------------------------------------------------------------------------
__global__ __launch_bounds__(256, 4) void msda_kernel(
    const float* __restrict__ query, const float* __restrict__ refp,
    const float* __restrict__ boff,  const float* __restrict__ battn,
    const float* __restrict__ bout,
    const short* __restrict__ WtH,   const short* __restrict__ WtL,
    const __half* __restrict__ v,    float* __restrict__ out)
{
    __shared__ __align__(16) char lds[32000];
    short*    sQh  = (short*)lds;                 // [16][264] bf16 hi (stage/E)
    short*    sQl  = (short*)(lds + 8448);        // [16][264] bf16 lo (stage/E)
    __half*   sWh  = (__half*)(lds + 16896);      // [16][264] attn wts -> preT (aliased)
    float*    sR   = (float*)(lds + 31488);       // [128] ref points

    const int t = threadIdx.x;
    const int n0 = blockIdx.x * 16;
    const int wv = t >> 6, lane = t & 63;
    const int mrow = lane & 15, kg = lane >> 4;
    float*    offW = (float*)lds + wv * 1056;     // per-wave [8][132] fp32 logits
    unsigned* sPI0 = (unsigned*)(lds + 25344 + wv * 768);
    uint2*    sPW0 = (uint2*)(lds + 25344 + wv * 768 + 256);
    unsigned* sPI1 = (unsigned*)(lds + 28416 + wv * 768);
    uint2*    sPW1 = (uint2*)(lds + 28416 + wv * 768 + 256);
    __half*   preT = sWh;                          // alias (row-disjoint in time)

    // ---- Stage: query -> bf16 hi/lo LDS, ref points ----
    for (int k2 = 0; k2 < 16; ++k2) {
        float x = query[(n0 + k2) * 256 + t];
        short hi = bf16hi(x);
        sQh[k2 * 264 + t] = hi;
        sQl[k2 * 264 + t] = bf16hi(x - bf16f(hi));
    }
    if (t < 128) sR[t] = refp[n0 * 8 + t];
    __syncthreads();

    // ---- Phase B: logits via MFMA (hi/lo 3-pass for off AND attn) ----
    f32x4 accO[8], accA[4];
    {
        f32x4 z = {0.f, 0.f, 0.f, 0.f};
        #pragma unroll
        for (int j = 0; j < 8; ++j) accO[j] = z;
        #pragma unroll
        for (int j = 0; j < 4; ++j) accA[j] = z;
    }
    {
        const short* offH = WtH + (wv * 128 + mrow) * 256 + kg * 8;
        const short* offLo = WtL + (wv * 128 + mrow) * 256 + kg * 8;
        const short* attH = WtH + (512 + wv * 64 + mrow) * 256 + kg * 8;
        const short* attL = WtL + (512 + wv * 64 + mrow) * 256 + kg * 8;
        const int aoff = mrow * 264 + kg * 8;
        #pragma unroll
        for (int kk = 0; kk < 8; ++kk) {
            s16x8 ah = *(const s16x8*)(sQh + aoff + kk * 32);
            s16x8 al = *(const s16x8*)(sQl + aoff + kk * 32);
            #pragma unroll
            for (int j = 0; j < 8; ++j) {
                s16x8 bh = *(const s16x8*)(offH + j * 4096 + kk * 32);
                s16x8 bl = *(const s16x8*)(offLo + j * 4096 + kk * 32);
                accO[j] = MFMA16(ah, bh, accO[j]);
                accO[j] = MFMA16(al, bh, accO[j]);
                accO[j] = MFMA16(ah, bl, accO[j]);
            }
            #pragma unroll
            for (int ja = 0; ja < 4; ++ja) {
                s16x8 bh = *(const s16x8*)(attH + ja * 4096 + kk * 32);
                s16x8 bl = *(const s16x8*)(attL + ja * 4096 + kk * 32);
                accA[ja] = MFMA16(ah, bh, accA[ja]);
                accA[ja] = MFMA16(al, bh, accA[ja]);
                accA[ja] = MFMA16(ah, bl, accA[ja]);
            }
        }
    }
    // biases (D layout: col = mrow, rows = kg*4 + r)
    #pragma unroll
    for (int j = 0; j < 8; ++j) {
        float bb = boff[wv * 128 + j * 16 + mrow];
        #pragma unroll
        for (int r = 0; r < 4; ++r) accO[j][r] += bb;
    }
    #pragma unroll
    for (int ja = 0; ja < 4; ++ja) {
        float bb = battn[wv * 64 + ja * 16 + mrow];
        #pragma unroll
        for (int r = 0; r < 4; ++r) accA[ja][r] += bb;
    }

    // ---- Softmax over P=8 (8-lane groups), fp16 weights to sWh (own heads) ----
    #pragma unroll
    for (int ja = 0; ja < 4; ++ja) {
        int hh = 2 * wv + (ja >> 1);
        int l  = ((ja & 1) << 1) | (mrow >> 3);
        int p  = mrow & 7;
        #pragma unroll
        for (int r = 0; r < 4; ++r) {
            float x = accA[ja][r];
            float m = fmaxf(x, __shfl_xor(x, 1));
            m = fmaxf(m, __shfl_xor(m, 2));
            m = fmaxf(m, __shfl_xor(m, 4));
            float e = __expf(x - m);
            float s = e + __shfl_xor(e, 1);
            s += __shfl_xor(s, 2);
            s += __shfl_xor(s, 4);
            int q = kg * 4 + r;
            sWh[q * 264 + hh * 32 + l * 8 + p] = __float2half_rn(e / s);
        }
    }
    __syncthreads();   // all waves done reading staged q; arena becomes offW

    // ---- Chunk-loop setup ----
    const int l_p = (lane >> 3) & 3, p_p = lane & 7, hhL_p = lane >> 5;
    const int Wl_p = 128 >> l_p;
    const float scl_p = 0.5f * (float)(Wl_p - 1);
    const int whCol = (2 * wv + hhL_p) * 32 + l_p * 8 + p_p;
    (void)p_p;
    const int sg = kg, ch2 = mrow;
    const int Wl_s = 128 >> sg;
    const int HWs = Wl_s * Wl_s;
    const int dyoMul = Wl_s * 16;
    const int VBs = (sg == 0) ? VB[0] : (sg == 1) ? VB[1] : (sg == 2) ? VB[2] : VB[3];
    const __half2* vl0 = (const __half2*)(v + VBs + (2 * wv) * HWs * 32) + ch2;
    const __half2* vl1 = (const __half2*)(v + VBs + (2 * wv + 1) * HWs * 32) + ch2;

    // ---- 2 superpasses x 8 queries, ping-pong pipelined ----
    for (int sp = 0; sp < 2; ++sp) {
        // dump: lanes holding q in [8sp, 8sp+8) write their accO rows
        if ((kg >> 1) == sp) {
            #pragma unroll
            for (int j = 0; j < 8; ++j)
                #pragma unroll
                for (int r = 0; r < 4; ++r)
                    offW[((kg & 1) * 4 + r) * 132 + j * 16 + mrow] = accO[j][r];
        }
        // prologue: pack first chunk of this superpass into buf0
        PACK_REC(sp * 8, sPI0, sPW0);

        #pragma unroll 2
        for (int c8 = 0; c8 < 8; ++c8) {
            const int chunk = sp * 8 + c8;
            unsigned* sPIc = (c8 & 1) ? sPI1 : sPI0;
            uint2*    sPWc = (c8 & 1) ? sPW1 : sPW0;
            unsigned* nPI  = (c8 & 1) ? sPI0 : sPI1;
            uint2*    nPW  = (c8 & 1) ? sPW0 : sPW1;

            #pragma unroll
            for (int hhL = 0; hhL < 2; ++hhL) {
                const __half2* vl = hhL ? vl1 : vl0;
                float ax = 0.f, ay = 0.f;
                #pragma unroll
                for (int pg = 0; pg < 2; ++pg) {
                    unsigned pwv[4]; uint2 wwv[4];
                    unsigned q00[4], q01[4], q10[4], q11[4];
                    #pragma unroll
                    for (int p4 = 0; p4 < 4; ++p4) {
                        int rec = hhL * 32 + sg * 8 + pg * 4 + p4;
                        pwv[p4] = sPIc[rec];
                        wwv[p4] = sPWc[rec];
                    }
                    #pragma unroll
                    for (int p4 = 0; p4 < 4; ++p4) {
                        int idx = pwv[p4] & 0x3FFF;
                        int dxo = ((pwv[p4] >> 14) & 1) * 16;
                        int dyo = ((pwv[p4] >> 15) & 1) * dyoMul;
                        const __half2* b00 = vl + idx * 16;
                        q00[p4] = *(const unsigned*)b00;
                        q01[p4] = *(const unsigned*)(b00 + dxo);
                        q10[p4] = *(const unsigned*)(b00 + dyo);
                        q11[p4] = *(const unsigned*)(b00 + dxo + dyo);
                    }
                    // overlap next-chunk pack under the gathers just issued
                    if (hhL == 0 && pg == 0 && c8 < 7) {
                        PACK_REC(chunk + 1, nPI, nPW);
                    }
                    #pragma unroll
                    for (int p4 = 0; p4 < 4; ++p4) {
                        float2 fa = __half22float2(*(__half2*)&wwv[p4].x);
                        float2 fb = __half22float2(*(__half2*)&wwv[p4].y);
                        float2 f00 = __half22float2(*(__half2*)&q00[p4]);
                        float2 f01 = __half22float2(*(__half2*)&q01[p4]);
                        float2 f10 = __half22float2(*(__half2*)&q10[p4]);
                        float2 f11 = __half22float2(*(__half2*)&q11[p4]);
                        ax += fa.x * f00.x + fa.y * f01.x + fb.x * f10.x + fb.y * f11.x;
                        ay += fa.x * f00.y + fa.y * f01.y + fb.x * f10.y + fb.y * f11.y;
                    }
                }
                float sxv = ax + __shfl_xor(ax, 16); sxv += __shfl_xor(sxv, 32);
                float syv = ay + __shfl_xor(ay, 16); syv += __shfl_xor(syv, 32);
                if (sg == 0)
                    *(__half2*)(preT + chunk * 264 + (2 * wv + hhL) * 32 + ch2 * 2) =
                        __floats2half2_rn(sxv, syv);
            }
        }
    }
    __syncthreads();

    // ---- E-stage: preT (fp16) -> bf16 hi/lo, then MFMA out projection ----
    {
        int q = t & 15, seg = t >> 4;        // row q, cols [seg*16, seg*16+16)
        const __half2* src = (const __half2*)(preT + q * 264 + seg * 16);
        short* dh = sQh + q * 264 + seg * 16;
        short* dl = sQl + q * 264 + seg * 16;
        #pragma unroll
        for (int jj = 0; jj < 8; ++jj) {
            float2 f = __half22float2(src[jj]);
            short h0 = bf16hi(f.x), h1 = bf16hi(f.y);
            dh[2 * jj]     = h0;
            dh[2 * jj + 1] = h1;
            dl[2 * jj]     = bf16hi(f.x - bf16f(h0));
            dl[2 * jj + 1] = bf16hi(f.y - bf16f(h1));
        }
    }
    __syncthreads();

    {
        f32x4 accE[4];
        f32x4 z = {0.f, 0.f, 0.f, 0.f};
        #pragma unroll
        for (int e = 0; e < 4; ++e) accE[e] = z;
        const short* outH = WtH + (768 + wv * 64 + mrow) * 256 + kg * 8;
        const short* outL = WtL + (768 + wv * 64 + mrow) * 256 + kg * 8;
        const int aoff = mrow * 264 + kg * 8;
        #pragma unroll
        for (int kk = 0; kk < 8; ++kk) {
            s16x8 ah = *(const s16x8*)(sQh + aoff + kk * 32);
            s16x8 al = *(const s16x8*)(sQl + aoff + kk * 32);
            #pragma unroll
            for (int e = 0; e < 4; ++e) {
                s16x8 bh = *(const s16x8*)(outH + e * 4096 + kk * 32);
                s16x8 bl = *(const s16x8*)(outL + e * 4096 + kk * 32);
                accE[e] = MFMA16(ah, bh, accE[e]);
                accE[e] = MFMA16(al, bh, accE[e]);
                accE[e] = MFMA16(ah, bl, accE[e]);
            }
        }
        #pragma unroll
        for (int e = 0; e < 4; ++e) {
            int col = wv * 64 + e * 16 + mrow;
            float bb = bout[col];
            #pragma unroll
            for (int r = 0; r < 4; ++r)
                out[(n0 + kg * 4 + r) * 256 + col] = accE[e][r] + bb;
        }
    }
}

// ---------------------------------------------------------------------------
extern "C" void kernel_launch(void* const* d_in, const int* in_sizes, int n_in,
                              void* d_out, int out_size, void* d_ws, size_t ws_size,
                              hipStream_t stream) {
    const float* query = (const float*)d_in[0];
    const float* refp  = (const float*)d_in[1];
    const float* f0    = (const float*)d_in[2];
    const float* f1    = (const float*)d_in[3];
    const float* f2    = (const float*)d_in[4];
    const float* f3    = (const float*)d_in[5];
    const float* Woff  = (const float*)d_in[6];
    const float* boff  = (const float*)d_in[7];
    const float* Wattn = (const float*)d_in[8];
    const float* battn = (const float*)d_in[9];
    const float* Wval  = (const float*)d_in[10];
    const float* bval  = (const float*)d_in[11];
    const float* Wout  = (const float*)d_in[12];
    const float* bout  = (const float*)d_in[13];

    __half* v  = (__half*)d_ws;                              // 11,141,120 B
    short* WtH = (short*)((char*)d_ws + 11141120);           //    524,288 B
    short* WtL = WtH + 262144;                               //    524,288 B
    float* outp = (float*)d_out;

    prep_w<<<1024, 256, 0, stream>>>(Woff, Wattn, Wout, WtH, WtL);
    vproj_kernel<<<1360, 256, 0, stream>>>(f0, f1, f2, f3, Wval, bval, v);
    msda_kernel<<<2500, 256, 0, stream>>>(query, refp, boff, battn, bout,
                                          WtH, WtL, v, outp);
}